// Round 2
// baseline (718.074 us; speedup 1.0000x reference)
//
#include <hip/hip_runtime.h>

typedef unsigned int u32;
typedef unsigned short u16;

constexpr int kB = 16, kT = 16, kN = 184, kD = 128, kH = 8, kHD = 16;
constexpr int kBT = kB * kT;            // 256
constexpr int kRows = kBT * kN;         // 47104
constexpr int kTile = kN * kHD;         // 2944 elements per (hb,t) tile

__device__ __forceinline__ float bf2f(u16 v) {
  return __uint_as_float(((u32)v) << 16);
}
__device__ __forceinline__ u16 f2bf(float f) {
  u32 x = __float_as_uint(f);
  x += 0x7fffu + ((x >> 16) & 1u);   // RNE
  return (u16)(x >> 16);
}
__device__ __forceinline__ void unpack2(u32 u, float& lo, float& hi) {
  lo = __uint_as_float(u << 16);
  hi = __uint_as_float(u & 0xffff0000u);
}
__device__ __forceinline__ void st8(float* dst, uint4 u) {
  unpack2(u.x, dst[0], dst[1]);
  unpack2(u.y, dst[2], dst[3]);
  unpack2(u.z, dst[4], dst[5]);
  unpack2(u.w, dst[6], dst[7]);
}
__device__ __forceinline__ float dot4(float4 a, float4 b) {
  return a.x * b.x + a.y * b.y + a.z * b.z + a.w * b.w;
}
__device__ __forceinline__ void fma4(float4& o, float s, float4 v) {
  o.x += s * v.x; o.y += s * v.y; o.z += s * v.z; o.w += s * v.w;
}
__device__ __forceinline__ void mul4(float4& o, float s) {
  o.x *= s; o.y *= s; o.z *= s; o.w *= s;
}

// ---------------------------------------------------------------------------
// Kernel 1: adp = ne1 @ ne2 [184,184] (fp32 in); row-softmax and col-softmax,
// both stored TRANSPOSED as bf16:
//   arowT[k*184+i] = rowsoftmax(adp)[i,k], acolT[k*184+i] = colsoftmax(adp)[k,i]
// Scores std ~3.2, |max| ~14: plain exp in fp32 is safe (== reference math).
// ---------------------------------------------------------------------------
__global__ __launch_bounds__(192) void adp_kernel(const float* __restrict__ ne1,
                                                  const float* __restrict__ ne2,
                                                  u16* __restrict__ arowT,
                                                  u16* __restrict__ acolT) {
  __shared__ float s1[kN * 10];   // ne1 [184][10]
  __shared__ float s2[10 * kN];   // ne2 [10][184]
  const int tid = threadIdx.x;
  for (int idx = tid; idx < kN * 10; idx += 192) {
    s1[idx] = ne1[idx];
    s2[idx] = ne2[idx];
  }
  __syncthreads();
  const int i = tid;
  if (i >= kN) return;

  float r1[10];
#pragma unroll
  for (int e = 0; e < 10; ++e) r1[e] = s1[i * 10 + e];

  // row i: a_ij = ne1[i,:] . ne2[:,j]
  float sum = 0.f;
  for (int j = 0; j < kN; ++j) {
    float a = 0.f;
#pragma unroll
    for (int e = 0; e < 10; ++e) a += r1[e] * s2[e * kN + j];
    sum += __expf(a);
  }
  float inv = 1.f / sum;
  for (int j = 0; j < kN; ++j) {
    float a = 0.f;
#pragma unroll
    for (int e = 0; e < 10; ++e) a += r1[e] * s2[e * kN + j];
    arowT[j * kN + i] = f2bf(__expf(a) * inv);
  }

  // column i: a_ki = ne1[k,:] . ne2[:,i]
  float c1[10];
#pragma unroll
  for (int e = 0; e < 10; ++e) c1[e] = s2[e * kN + i];
  sum = 0.f;
  for (int kk = 0; kk < kN; ++kk) {
    float a = 0.f;
#pragma unroll
    for (int e = 0; e < 10; ++e) a += s1[kk * 10 + e] * c1[e];
    sum += __expf(a);
  }
  inv = 1.f / sum;
  for (int kk = 0; kk < kN; ++kk) {
    float a = 0.f;
#pragma unroll
    for (int e = 0; e < 10; ++e) a += s1[kk * 10 + e] * c1[e];
    acolT[kk * kN + i] = f2bf(__expf(a) * inv);
  }
}

// ---------------------------------------------------------------------------
// Kernel 2: q/k/v projection GEMM [47104 x 128] @ [128 x 128]^T + bias (fp32),
// output bf16 in split-head layout [H, B*T, N, 16]. W streamed from global
// (L2-hot, 64 FMAs per 16B load); only the 32x128 input tile is LDS-staged.
// ---------------------------------------------------------------------------
__global__ __launch_bounds__(256) void proj_kernel(
    const float* __restrict__ qin, const float* __restrict__ kin, const float* __restrict__ vin,
    const float* __restrict__ Wq, const float* __restrict__ bq,
    const float* __restrict__ Wk, const float* __restrict__ bk,
    const float* __restrict__ Wv, const float* __restrict__ bv,
    u16* __restrict__ qo, u16* __restrict__ ko, u16* __restrict__ vo) {
  __shared__ float s_in[32 * 128];
  __shared__ float s_b[128];

  const float* in; const float* W; const float* bias; u16* out;
  if (blockIdx.y == 0)      { in = qin; W = Wq; bias = bq; out = qo; }
  else if (blockIdx.y == 1) { in = kin; W = Wk; bias = bk; out = ko; }
  else                      { in = vin; W = Wv; bias = bv; out = vo; }

  const int tid = threadIdx.x;
  const int r0 = blockIdx.x * 32;

  const float4* src = (const float4*)(in + (size_t)r0 * 128);
  float4* dst = (float4*)s_in;
  for (int idx = tid; idx < 1024; idx += 256) dst[idx] = src[idx];
  if (tid < 128) s_b[tid] = bias[tid];
  __syncthreads();

  const int c = tid & 127;   // output column
  const int rh = tid >> 7;   // row half (0/1)
  float acc[16];
#pragma unroll
  for (int i2 = 0; i2 < 16; ++i2) acc[i2] = 0.f;

  for (int k0 = 0; k0 < 128; k0 += 4) {
    const float4 w = *(const float4*)&W[c * 128 + k0];
#pragma unroll
    for (int i2 = 0; i2 < 16; ++i2) {
      const float4 x = *(const float4*)&s_in[(rh + 2 * i2) * 128 + k0];
      acc[i2] += x.x * w.x + x.y * w.y + x.z * w.z + x.w * w.w;
    }
  }

  const int h = c >> 4, hd = c & 15;
#pragma unroll
  for (int i2 = 0; i2 < 16; ++i2) {
    const int r = r0 + rh + 2 * i2;
    const int n = r % kN;
    const int bt = r / kN;
    out[(size_t)((h * kBT + bt) * kN + n) * 16 + hd] = f2bf(acc[i2] + s_b[c]);
  }
}

// ---------------------------------------------------------------------------
// Kernel 3: per-(hb,t) dual-softmax attention + adp mixing + fused Wm.
// One block per (hb*T + t); thread i owns output row i (i < 184).
// No max-subtraction (logits std ~0.33; fp32 exp exact vs reference).
// NOTE: mg aliases qg (per-tile read-then-overwrite; blocks touch disjoint
// tiles, reads complete before the barrier) -> no __restrict__ on those two.
// ---------------------------------------------------------------------------
__global__ __launch_bounds__(192) void attn_kernel(
    const u16* qg, const u16* __restrict__ kg, const u16* __restrict__ vg,
    const u16* __restrict__ arowT, const u16* __restrict__ acolT,
    const float* __restrict__ Wm, const float* __restrict__ bm,
    u16* mg) {
  __shared__ float s_q[kTile];
  __shared__ float s_k[kTile];
  __shared__ float s_v[kTile];
  __shared__ float s_wm[16 * 64];
  __shared__ float s_bm[16];

  const int tid = threadIdx.x;
  const int base = blockIdx.x * kTile;

  const uint4* q4g = (const uint4*)(qg + base);
  const uint4* k4g = (const uint4*)(kg + base);
  const uint4* v4g = (const uint4*)(vg + base);
  for (int idx = tid; idx < kTile / 8; idx += 192) {
    st8(&s_q[idx * 8], q4g[idx]);
    st8(&s_k[idx * 8], k4g[idx]);
    st8(&s_v[idx * 8], v4g[idx]);
  }
  for (int idx = tid; idx < 1024; idx += 192) s_wm[idx] = Wm[idx];
  if (tid < 16) s_bm[tid] = bm[tid];
  __syncthreads();

  const int i = tid;
  if (i >= kN) return;

  const float4* q4 = (const float4*)s_q;
  const float4* k4 = (const float4*)s_k;
  const float4* v4 = (const float4*)s_v;

  float4 o1a = {0,0,0,0}, o1b = {0,0,0,0}, o1c = {0,0,0,0}, o1d = {0,0,0,0};
  float4 o2a = {0,0,0,0}, o2b = {0,0,0,0}, o2c = {0,0,0,0}, o2d = {0,0,0,0};
  float4 o3a = {0,0,0,0}, o3b = {0,0,0,0}, o3c = {0,0,0,0}, o3d = {0,0,0,0};
  float4 o4a = {0,0,0,0}, o4b = {0,0,0,0}, o4c = {0,0,0,0}, o4d = {0,0,0,0};

  // ---- row-softmax pass (o1): thread i = query row i
  float4 ra = q4[i * 4 + 0], rb = q4[i * 4 + 1], rc = q4[i * 4 + 2], rd = q4[i * 4 + 3];
  float l1 = 0.f;
  for (int j = 0; j < kN; ++j) {
    const float s = dot4(ra, k4[j * 4 + 0]) + dot4(rb, k4[j * 4 + 1]) +
                    dot4(rc, k4[j * 4 + 2]) + dot4(rd, k4[j * 4 + 3]);
    const float p = __expf(s * 0.25f);
    l1 += p;
    const float4 va = v4[j * 4 + 0], vb = v4[j * 4 + 1], vc = v4[j * 4 + 2], vd = v4[j * 4 + 3];
    fma4(o1a, p, va); fma4(o1b, p, vb); fma4(o1c, p, vc); fma4(o1d, p, vd);
  }

  // ---- col-softmax pass (o2): thread i = key row i, weights over k
  ra = k4[i * 4 + 0]; rb = k4[i * 4 + 1]; rc = k4[i * 4 + 2]; rd = k4[i * 4 + 3];
  float l2 = 0.f;
  for (int j = 0; j < kN; ++j) {
    const float s = dot4(ra, q4[j * 4 + 0]) + dot4(rb, q4[j * 4 + 1]) +
                    dot4(rc, q4[j * 4 + 2]) + dot4(rd, q4[j * 4 + 3]);
    const float p = __expf(s * 0.25f);
    l2 += p;
    const float4 va = v4[j * 4 + 0], vb = v4[j * 4 + 1], vc = v4[j * 4 + 2], vd = v4[j * 4 + 3];
    fma4(o2a, p, va); fma4(o2b, p, vb); fma4(o2c, p, vc); fma4(o2d, p, vd);
  }

  // ---- adp mixes (o3, o4): coalesced transposed weight loads
  for (int j = 0; j < kN; ++j) {
    const float a3 = bf2f(arowT[j * kN + i]);
    const float a4 = bf2f(acolT[j * kN + i]);
    const float4 va = v4[j * 4 + 0], vb = v4[j * 4 + 1], vc = v4[j * 4 + 2], vd = v4[j * 4 + 3];
    fma4(o3a, a3, va); fma4(o3b, a3, vb); fma4(o3c, a3, vc); fma4(o3d, a3, vd);
    fma4(o4a, a4, va); fma4(o4b, a4, vb); fma4(o4c, a4, vc); fma4(o4d, a4, vd);
  }

  const float n1 = 1.f / l1, n2 = 1.f / l2;
  mul4(o1a, n1); mul4(o1b, n1); mul4(o1c, n1); mul4(o1d, n1);
  mul4(o2a, n2); mul4(o2b, n2); mul4(o2c, n2); mul4(o2d, n2);

  // ---- fused Wm: m[c] = bm[c] + Wm[c,:] . [o1|o2|o3|o4]
  const float4* wm4 = (const float4*)s_wm;
  u32* mo = (u32*)(mg + base + i * 16);
#pragma unroll
  for (int c = 0; c < 16; c += 2) {
    const float4* w0 = &wm4[c * 16];
    const float4* w1 = &wm4[(c + 1) * 16];
    float m0 = s_bm[c] +
        dot4(o1a, w0[0])  + dot4(o1b, w0[1])  + dot4(o1c, w0[2])  + dot4(o1d, w0[3]) +
        dot4(o2a, w0[4])  + dot4(o2b, w0[5])  + dot4(o2c, w0[6])  + dot4(o2d, w0[7]) +
        dot4(o3a, w0[8])  + dot4(o3b, w0[9])  + dot4(o3c, w0[10]) + dot4(o3d, w0[11]) +
        dot4(o4a, w0[12]) + dot4(o4b, w0[13]) + dot4(o4c, w0[14]) + dot4(o4d, w0[15]);
    float m1 = s_bm[c + 1] +
        dot4(o1a, w1[0])  + dot4(o1b, w1[1])  + dot4(o1c, w1[2])  + dot4(o1d, w1[3]) +
        dot4(o2a, w1[4])  + dot4(o2b, w1[5])  + dot4(o2c, w1[6])  + dot4(o2d, w1[7]) +
        dot4(o3a, w1[8])  + dot4(o3b, w1[9])  + dot4(o3c, w1[10]) + dot4(o3d, w1[11]) +
        dot4(o4a, w1[12]) + dot4(o4b, w1[13]) + dot4(o4c, w1[14]) + dot4(o4d, w1[15]);
    mo[c >> 1] = (u32)f2bf(m0) | ((u32)f2bf(m1) << 16);
  }
}

// ---------------------------------------------------------------------------
// Kernel 4: head merge (gather bf16) + Wo GEMM [47104x128]@[128x128]^T + bo,
// fp32 output. Wo streamed from global (L2-hot).
// ---------------------------------------------------------------------------
__global__ __launch_bounds__(256) void out_kernel(
    const u16* __restrict__ mg, const float* __restrict__ Wo, const float* __restrict__ bo,
    float* __restrict__ outg) {
  __shared__ float s_in[32 * 128];
  __shared__ float s_b[128];
  const int tid = threadIdx.x;
  const int r0 = blockIdx.x * 32;

  {
    const int rr = tid >> 3;   // 0..31 row in tile
    const int h = tid & 7;     // head
    const int r = r0 + rr;
    const int n = r % kN;
    const int bt = r / kN;
    const uint4* src = (const uint4*)(mg + (size_t)((h * kBT + bt) * kN + n) * 16);
    st8(&s_in[rr * 128 + h * 16 + 0], src[0]);
    st8(&s_in[rr * 128 + h * 16 + 8], src[1]);
  }
  if (tid < 128) s_b[tid] = bo[tid];
  __syncthreads();

  const int c = tid & 127;
  const int rh = tid >> 7;
  float acc[16];
#pragma unroll
  for (int i2 = 0; i2 < 16; ++i2) acc[i2] = 0.f;

  for (int k0 = 0; k0 < 128; k0 += 4) {
    const float4 w = *(const float4*)&Wo[c * 128 + k0];
#pragma unroll
    for (int i2 = 0; i2 < 16; ++i2) {
      const float4 x = *(const float4*)&s_in[(rh + 2 * i2) * 128 + k0];
      acc[i2] += x.x * w.x + x.y * w.y + x.z * w.z + x.w * w.w;
    }
  }
#pragma unroll
  for (int i2 = 0; i2 < 16; ++i2) {
    const int r = r0 + rh + 2 * i2;
    outg[(size_t)r * 128 + c] = acc[i2] + s_b[c];
  }
}

// ---------------------------------------------------------------------------
extern "C" void kernel_launch(void* const* d_in, const int* in_sizes, int n_in,
                              void* d_out, int out_size, void* d_ws, size_t ws_size,
                              hipStream_t stream) {
  const float* query = (const float*)d_in[0];
  const float* key   = (const float*)d_in[1];
  const float* value = (const float*)d_in[2];
  const float* Wq = (const float*)d_in[3];
  const float* bq = (const float*)d_in[4];
  const float* Wk = (const float*)d_in[5];
  const float* bk = (const float*)d_in[6];
  const float* Wv = (const float*)d_in[7];
  const float* bv = (const float*)d_in[8];
  const float* Wm = (const float*)d_in[9];
  const float* bm = (const float*)d_in[10];
  const float* Wo = (const float*)d_in[11];
  const float* bo = (const float*)d_in[12];
  const float* ne1 = (const float*)d_in[13];
  const float* ne2 = (const float*)d_in[14];
  // d_in[15] = dim (always 2 for this problem instance)

  // workspace layout (bytes): q(/m), k, v split-head bf16 + adp tables
  const size_t tensor_bytes = (size_t)kH * kB * kT * kN * kHD * 2;  // 12,058,624
  char* ws = (char*)d_ws;
  u16* qs    = (u16*)(ws);                      // reused as m after attn
  u16* ks    = (u16*)(ws + tensor_bytes);
  u16* vs    = (u16*)(ws + 2 * tensor_bytes);
  u16* arowT = (u16*)(ws + 3 * tensor_bytes);
  u16* acolT = (u16*)(ws + 3 * tensor_bytes + (size_t)kN * kN * 2);
  // total: 36,311,296 bytes

  adp_kernel<<<1, 192, 0, stream>>>(ne1, ne2, arowT, acolT);
  proj_kernel<<<dim3(kRows / 32, 3), 256, 0, stream>>>(
      query, key, value, Wq, bq, Wk, bk, Wv, bv, qs, ks, vs);
  attn_kernel<<<kH * kB * kT, 192, 0, stream>>>(qs, ks, vs, arowT, acolT, Wm, bm, qs);
  out_kernel<<<kRows / 32, 256, 0, stream>>>(qs, Wo, bo, (float*)d_out);
}

// Round 3
// 419.176 us; speedup vs baseline: 1.7131x; 1.7131x over previous
//
#include <hip/hip_runtime.h>

typedef unsigned int u32;
typedef unsigned short u16;
typedef unsigned long long ull;

constexpr int kB = 16, kT = 16, kN = 184, kD = 128, kH = 8, kHD = 16;
constexpr int kBT = kB * kT;            // 256
constexpr int kRows = kBT * kN;         // 47104
constexpr int kTile = kN * kHD;         // 2944 elements per (hb,t) tile

typedef __attribute__((ext_vector_type(8))) short bf16x8;
typedef __attribute__((ext_vector_type(4))) float f32x4;

union FragU {
  bf16x8 f;
  ull u[2];
  uint4 q;
  u16 h[8];
};

#define MFMA(a, b, c) __builtin_amdgcn_mfma_f32_16x16x32_bf16((a), (b), (c), 0, 0, 0)

__device__ __forceinline__ float bf2f(u16 v) {
  return __uint_as_float(((u32)v) << 16);
}
__device__ __forceinline__ u16 f2bf(float f) {
  u32 x = __float_as_uint(f);
  x += 0x7fffu + ((x >> 16) & 1u);   // RNE
  return (u16)(x >> 16);
}
__device__ __forceinline__ void unpack2(u32 u, float& lo, float& hi) {
  lo = __uint_as_float(u << 16);
  hi = __uint_as_float(u & 0xffff0000u);
}
__device__ __forceinline__ void st8(float* dst, uint4 u) {
  unpack2(u.x, dst[0], dst[1]);
  unpack2(u.y, dst[2], dst[3]);
  unpack2(u.z, dst[4], dst[5]);
  unpack2(u.w, dst[6], dst[7]);
}

// A/B fragment from row-major [192][16] bf16 tile store (stride 20 u16).
// Element j = tile[lane&15][quad*8+j]; quads 2,3 are K-padding -> 0.
// (Contiguous row read as B-operand yields B = tile^T, which is what S=Q@K^T
//  and the staging-transpose tricks below rely on.)
__device__ __forceinline__ bf16x8 ld_qk_frag(const u16* s, int tile, int lane) {
  FragU f;
  f.u[0] = 0; f.u[1] = 0;
  const int quad = lane >> 4;
  if (quad < 2) {
    const ull* p = (const ull*)(s + (tile * 16 + (lane & 15)) * 20 + quad * 8);
    f.u[0] = p[0];
    f.u[1] = p[1];
  }
  return f.f;
}

// ---------------------------------------------------------------------------
// Kernel 1: adp = ne1 @ ne2 [184,184] fp32; writes BOTH softmaxed matrices
// pre-baked in MFMA A-fragment pair order (K=32 pairs), bf16, zero-padded
// to 192: arr3 = adp_row fragments, arr4 = adp_col^T fragments.
// Entry e = (i*6+p)*64 + lane; 8 bf16 = A[m=lane&15][kd=quad*8+j] of the
// (i-th 16-row tile, p-th 32-col pair).
// ---------------------------------------------------------------------------
__global__ __launch_bounds__(256) void adp_kernel(
    const float* __restrict__ ne1, const float* __restrict__ ne2,
    u16* __restrict__ arr3, u16* __restrict__ arr4) {
  __shared__ float s1[kN * 10];
  __shared__ float s2[10 * kN];
  __shared__ float l1r[kN];
  __shared__ float l2c[kN];
  const int tid = threadIdx.x;
  for (int i = tid; i < kN * 10; i += 256) { s1[i] = ne1[i]; s2[i] = ne2[i]; }
  __syncthreads();

  if (tid < kN) {
    const int r = tid;
    float reg[10];
#pragma unroll
    for (int e = 0; e < 10; ++e) reg[e] = s1[r * 10 + e];
    float sum = 0.f;
    for (int c = 0; c < kN; ++c) {
      float d = 0.f;
#pragma unroll
      for (int e = 0; e < 10; ++e) d += reg[e] * s2[e * kN + c];
      sum += __expf(d);
    }
    l1r[r] = sum;

    const int c = tid;
    float regc[10];
#pragma unroll
    for (int e = 0; e < 10; ++e) regc[e] = s2[e * kN + c];
    sum = 0.f;
    for (int r2 = 0; r2 < kN; ++r2) {
      float d = 0.f;
#pragma unroll
      for (int e = 0; e < 10; ++e) d += s1[r2 * 10 + e] * regc[e];
      sum += __expf(d);
    }
    l2c[c] = sum;
  }
  __syncthreads();

  for (int ee = tid; ee < 12 * 6 * 64; ee += 256) {
    const int i = ee / 384;
    const int rem = ee - i * 384;
    const int p = rem >> 6;
    const int lane = rem & 63;
    const int row = i * 16 + (lane & 15);
    const int cb = p * 32 + (lane >> 4) * 8;
    FragU fo3, fo4;
    const bool rok = row < kN;
    float inv1 = 0.f, inv2 = 0.f;
    float rreg[10], creg[10];
    if (rok) {
      inv1 = 1.f / l1r[row];
      inv2 = 1.f / l2c[row];
#pragma unroll
      for (int e = 0; e < 10; ++e) {
        rreg[e] = s1[row * 10 + e];      // ne1 row 'row'  (arr3 dots)
        creg[e] = s2[e * kN + row];      // ne2 col 'row'  (arr4 dots)
      }
    }
#pragma unroll
    for (int j = 0; j < 8; ++j) {
      const int col = cb + j;
      float v3 = 0.f, v4 = 0.f;
      if (rok && col < kN) {
        float d3 = 0.f, d4 = 0.f;
#pragma unroll
        for (int e = 0; e < 10; ++e) {
          d3 += rreg[e] * s2[e * kN + col];
          d4 += s1[col * 10 + e] * creg[e];
        }
        v3 = __expf(d3) * inv1;            // adp_row[row][col]
        v4 = __expf(d4) * inv2;            // adp_col[col][row] = adp_col^T[row][col]
      }
      fo3.h[j] = f2bf(v3);
      fo4.h[j] = f2bf(v4);
    }
    *(uint4*)(arr3 + (size_t)ee * 8) = fo3.q;
    *(uint4*)(arr4 + (size_t)ee * 8) = fo4.q;
  }
}

// ---------------------------------------------------------------------------
// Kernel 2: q/k/v projection GEMM [47104 x 128] @ [128 x 128]^T + bias (fp32),
// output bf16 in split-head layout [H, B*T, N, 16]. (unchanged from r2)
// ---------------------------------------------------------------------------
__global__ __launch_bounds__(256) void proj_kernel(
    const float* __restrict__ qin, const float* __restrict__ kin, const float* __restrict__ vin,
    const float* __restrict__ Wq, const float* __restrict__ bq,
    const float* __restrict__ Wk, const float* __restrict__ bk,
    const float* __restrict__ Wv, const float* __restrict__ bv,
    u16* __restrict__ qo, u16* __restrict__ ko, u16* __restrict__ vo) {
  __shared__ float s_in[32 * 128];
  __shared__ float s_b[128];

  const float* in; const float* W; const float* bias; u16* out;
  if (blockIdx.y == 0)      { in = qin; W = Wq; bias = bq; out = qo; }
  else if (blockIdx.y == 1) { in = kin; W = Wk; bias = bk; out = ko; }
  else                      { in = vin; W = Wv; bias = bv; out = vo; }

  const int tid = threadIdx.x;
  const int r0 = blockIdx.x * 32;

  const float4* src = (const float4*)(in + (size_t)r0 * 128);
  float4* dst = (float4*)s_in;
  for (int idx = tid; idx < 1024; idx += 256) dst[idx] = src[idx];
  if (tid < 128) s_b[tid] = bias[tid];
  __syncthreads();

  const int c = tid & 127;
  const int rh = tid >> 7;
  float acc[16];
#pragma unroll
  for (int i2 = 0; i2 < 16; ++i2) acc[i2] = 0.f;

  for (int k0 = 0; k0 < 128; k0 += 4) {
    const float4 w = *(const float4*)&W[c * 128 + k0];
#pragma unroll
    for (int i2 = 0; i2 < 16; ++i2) {
      const float4 x = *(const float4*)&s_in[(rh + 2 * i2) * 128 + k0];
      acc[i2] += x.x * w.x + x.y * w.y + x.z * w.z + x.w * w.w;
    }
  }

  const int h = c >> 4, hd = c & 15;
#pragma unroll
  for (int i2 = 0; i2 < 16; ++i2) {
    const int r = r0 + rh + 2 * i2;
    const int n = r % kN;
    const int bt = r / kN;
    out[(size_t)((h * kBT + bt) * kN + n) * 16 + hd] = f2bf(acc[i2] + s_b[c]);
  }
}

// ---------------------------------------------------------------------------
// Kernel 3: MFMA dual-softmax attention + adp mixing + fused Wm.
// One block = one (hb,t) tile. 4 waves; wave w owns token-tiles {w,w+4,w+8}.
// Row pass: S-tile(i,k)=mfma(Qf,Kf) -> C holds E[i*16+qrow][k*16+col];
//   stage row-major into pair buffer -> b128 A-frag -> o1 += P@V, l1 += P@1.
// Col pass: S-tile(r,c) staged TRANSPOSED -> A-frag of E^T -> o2,l2.
// Normalization: o1/l1, o2/l2 land in matching lane/reg (ones-MFMA trick).
// adp fragments pre-baked by adp_kernel (L2-hot dwordx4 loads).
// Wm fused: cat staged to LDS, 2 MFMAs (K=32 x2) + bias.
// mg aliases qg (tile fully read into LDS before any write).
// ---------------------------------------------------------------------------
__global__ __launch_bounds__(256) void attn_kernel(
    const u16* qg, const u16* __restrict__ kg, const u16* __restrict__ vg,
    const u16* __restrict__ arr3, const u16* __restrict__ arr4,
    const float* __restrict__ Wm, const float* __restrict__ bm,
    u16* mg) {
  __shared__ u16 s_q[192 * 20];    // row-major, stride 20 u16 (40B, 8B-aligned rows)
  __shared__ u16 s_k[192 * 20];
  __shared__ u16 s_vT[16 * 200];   // transposed V: [ch][token], stride 200 (16B-aligned)
  __shared__ u16 s_stage[4 * 640]; // per-wave 16x40 P-pair staging
  __shared__ u16 s_cat[4 * 1152];  // per-wave 16x72 cat staging

  const int tid = threadIdx.x;
  const size_t base = (size_t)blockIdx.x * kTile;

  // ---- stage q,k (row-major, zero-pad tokens 184..191) and v (transposed)
  for (int idx8 = tid; idx8 < 384; idx8 += 256) {
    const int t = idx8 >> 1, c0 = (idx8 & 1) * 8;
    ull zq0 = 0, zq1 = 0, zk0 = 0, zk1 = 0;
    if (t < kN) {
      const ull* qp = (const ull*)(qg + base + t * 16 + c0);
      const ull* kp = (const ull*)(kg + base + t * 16 + c0);
      zq0 = qp[0]; zq1 = qp[1];
      zk0 = kp[0]; zk1 = kp[1];
    }
    ull* dq = (ull*)(s_q + t * 20 + c0);
    ull* dk = (ull*)(s_k + t * 20 + c0);
    dq[0] = zq0; dq[1] = zq1;
    dk[0] = zk0; dk[1] = zk1;
  }
  for (int idx = tid; idx < 3072; idx += 256) {
    const int t = idx >> 4, ch = idx & 15;
    s_vT[ch * 200 + t] = (t < kN) ? vg[base + idx] : (u16)0;
  }
  __syncthreads();

  const int w = tid >> 6, lane = tid & 63;
  const int quad = lane >> 4, m = lane & 15;

  // ---- per-wave persistent fragments
  bf16x8 vb[6];   // V B-frags: B[kd][n]=V[32p+kd][n] = s_vT[n][32p+kd]
#pragma unroll
  for (int p = 0; p < 6; ++p) {
    FragU f;
    f.q = *(const uint4*)(s_vT + m * 200 + p * 32 + quad * 8);
    vb[p] = f.f;
  }
  FragU onesU; onesU.u[0] = 0x3F803F803F803F80ULL; onesU.u[1] = onesU.u[0];
  const bf16x8 ones = onesU.f;

  bf16x8 wmb[2];  // Wm^T B-frags: B[kd][n]=Wm[n][kt*32+kd]
#pragma unroll
  for (int kt = 0; kt < 2; ++kt) {
    const float* wp = Wm + m * 64 + kt * 32 + quad * 8;
    FragU f;
#pragma unroll
    for (int j = 0; j < 8; ++j) f.h[j] = f2bf(wp[j]);
    wmb[kt] = f.f;
  }
  const float bmv = bm[m];

  u16* stg = s_stage + w * 640;
  u16* cw = s_cat + w * 1152;
  const f32x4 zero4 = {0.f, 0.f, 0.f, 0.f};

  for (int tt = w; tt < 12; tt += 4) {
    // ================= row pass (i = tt) =================
    f32x4 o1 = zero4, l1 = zero4, o3 = zero4, o4 = zero4;
    const bf16x8 qf = ld_qk_frag(s_q, tt, lane);
#pragma unroll
    for (int p = 0; p < 6; ++p) {
#pragma unroll
      for (int h = 0; h < 2; ++h) {
        const int k = p * 2 + h;
        const bf16x8 kf = ld_qk_frag(s_k, k, lane);
        f32x4 sv = MFMA(qf, kf, zero4);   // C: E-tile[row=quad*4+r][col=m]
        const bool kill = (k == 11) && (m >= 8);   // pad cols -> exp must be 0
#pragma unroll
        for (int r = 0; r < 4; ++r) {
          const float ev = kill ? 0.f : __expf(sv[r] * 0.25f);
          stg[(quad * 4 + r) * 40 + h * 16 + m] = f2bf(ev);
        }
      }
      FragU pa; pa.q = *(const uint4*)(stg + m * 40 + quad * 8);
      o1 = MFMA(pa.f, vb[p], o1);
      l1 = MFMA(pa.f, ones, l1);
      FragU a3; a3.q = *(const uint4*)(arr3 + (size_t)((tt * 6 + p) * 64 + lane) * 8);
      FragU a4; a4.q = *(const uint4*)(arr4 + (size_t)((tt * 6 + p) * 64 + lane) * 8);
      o3 = MFMA(a3.f, vb[p], o3);
      o4 = MFMA(a4.f, vb[p], o4);
    }
    // ================= col pass (c = tt) =================
    f32x4 o2 = zero4, l2 = zero4;
    const bf16x8 kfc = ld_qk_frag(s_k, tt, lane);
#pragma unroll
    for (int p = 0; p < 6; ++p) {
#pragma unroll
      for (int h = 0; h < 2; ++h) {
        const int r = p * 2 + h;
        const bf16x8 qf2 = ld_qk_frag(s_q, r, lane);
        f32x4 sv = MFMA(qf2, kfc, zero4); // C: E[r*16+quad*4+rr][c*16+m]
        const bool kill = (r == 11) && (quad >= 2);  // pad rows of E
#pragma unroll
        for (int rr = 0; rr < 4; ++rr) {
          const float ev = kill ? 0.f : __expf(sv[rr] * 0.25f);
          // transposed staging: stagingT[col m][kd = h*16 + quad*4+rr]
          stg[m * 40 + h * 16 + quad * 4 + rr] = f2bf(ev);
        }
      }
      FragU pa; pa.q = *(const uint4*)(stg + m * 40 + quad * 8);  // A of E^T
      o2 = MFMA(pa.f, vb[p], o2);
      l2 = MFMA(pa.f, ones, l2);
    }
    // ================= fused Wm epilogue =================
#pragma unroll
    for (int r = 0; r < 4; ++r) {
      const int rowbase = (quad * 4 + r) * 72;
      cw[rowbase + m]      = f2bf(o1[r] / l1[r]);
      cw[rowbase + 16 + m] = f2bf(o2[r] / l2[r]);
      cw[rowbase + 32 + m] = f2bf(o3[r]);
      cw[rowbase + 48 + m] = f2bf(o4[r]);
    }
    f32x4 macc = {bmv, bmv, bmv, bmv};
#pragma unroll
    for (int kt = 0; kt < 2; ++kt) {
      FragU ca; ca.q = *(const uint4*)(cw + m * 72 + kt * 32 + quad * 8);
      macc = MFMA(ca.f, wmb[kt], macc);
    }
#pragma unroll
    for (int r = 0; r < 4; ++r) {
      const int row = tt * 16 + quad * 4 + r;
      if (row < kN) mg[base + row * 16 + m] = f2bf(macc[r]);
    }
  }
}

// ---------------------------------------------------------------------------
// Kernel 4: head merge (gather bf16) + Wo GEMM [47104x128]@[128x128]^T + bo,
// fp32 output. (unchanged from r2)
// ---------------------------------------------------------------------------
__global__ __launch_bounds__(256) void out_kernel(
    const u16* __restrict__ mg, const float* __restrict__ Wo, const float* __restrict__ bo,
    float* __restrict__ outg) {
  __shared__ float s_in[32 * 128];
  __shared__ float s_b[128];
  const int tid = threadIdx.x;
  const int r0 = blockIdx.x * 32;

  {
    const int rr = tid >> 3;
    const int h = tid & 7;
    const int r = r0 + rr;
    const int n = r % kN;
    const int bt = r / kN;
    const uint4* src = (const uint4*)(mg + (size_t)((h * kBT + bt) * kN + n) * 16);
    st8(&s_in[rr * 128 + h * 16 + 0], src[0]);
    st8(&s_in[rr * 128 + h * 16 + 8], src[1]);
  }
  if (tid < 128) s_b[tid] = bo[tid];
  __syncthreads();

  const int c = tid & 127;
  const int rh = tid >> 7;
  float acc[16];
#pragma unroll
  for (int i2 = 0; i2 < 16; ++i2) acc[i2] = 0.f;

  for (int k0 = 0; k0 < 128; k0 += 4) {
    const float4 w = *(const float4*)&Wo[c * 128 + k0];
#pragma unroll
    for (int i2 = 0; i2 < 16; ++i2) {
      const float4 x = *(const float4*)&s_in[(rh + 2 * i2) * 128 + k0];
      acc[i2] += x.x * w.x + x.y * w.y + x.z * w.z + x.w * w.w;
    }
  }
#pragma unroll
  for (int i2 = 0; i2 < 16; ++i2) {
    const int r = r0 + rh + 2 * i2;
    outg[(size_t)r * 128 + c] = acc[i2] + s_b[c];
  }
}

// ---------------------------------------------------------------------------
extern "C" void kernel_launch(void* const* d_in, const int* in_sizes, int n_in,
                              void* d_out, int out_size, void* d_ws, size_t ws_size,
                              hipStream_t stream) {
  const float* query = (const float*)d_in[0];
  const float* key   = (const float*)d_in[1];
  const float* value = (const float*)d_in[2];
  const float* Wq = (const float*)d_in[3];
  const float* bq = (const float*)d_in[4];
  const float* Wk = (const float*)d_in[5];
  const float* bk = (const float*)d_in[6];
  const float* Wv = (const float*)d_in[7];
  const float* bv = (const float*)d_in[8];
  const float* Wm = (const float*)d_in[9];
  const float* bm = (const float*)d_in[10];
  const float* Wo = (const float*)d_in[11];
  const float* bo = (const float*)d_in[12];
  const float* ne1 = (const float*)d_in[13];
  const float* ne2 = (const float*)d_in[14];
  // d_in[15] = dim (always 2 for this problem instance)

  const size_t tensor_bytes = (size_t)kH * kB * kT * kN * kHD * 2;  // 12,058,624
  const size_t frag_bytes = (size_t)12 * 6 * 64 * 8 * 2;            // 73,728
  char* ws = (char*)d_ws;
  u16* qs   = (u16*)(ws);                        // reused as m after attn
  u16* ks   = (u16*)(ws + tensor_bytes);
  u16* vs   = (u16*)(ws + 2 * tensor_bytes);
  u16* arr3 = (u16*)(ws + 3 * tensor_bytes);
  u16* arr4 = (u16*)(ws + 3 * tensor_bytes + frag_bytes);
  // total: ~36.5 MB

  adp_kernel<<<1, 256, 0, stream>>>(ne1, ne2, arr3, arr4);
  proj_kernel<<<dim3(kRows / 32, 3), 256, 0, stream>>>(
      query, key, value, Wq, bq, Wk, bk, Wv, bv, qs, ks, vs);
  attn_kernel<<<kH * kB * kT, 256, 0, stream>>>(qs, ks, vs, arr3, arr4, Wm, bm, qs);
  out_kernel<<<kRows / 32, 256, 0, stream>>>(qs, Wo, bo, (float*)d_out);
}

// Round 4
// 284.604 us; speedup vs baseline: 2.5231x; 1.4728x over previous
//
#include <hip/hip_runtime.h>

typedef unsigned int u32;
typedef unsigned short u16;
typedef unsigned long long ull;

constexpr int kB = 16, kT = 16, kN = 184, kD = 128, kH = 8, kHD = 16;
constexpr int kBT = kB * kT;            // 256
constexpr int kRows = kBT * kN;         // 47104
constexpr int kTile = kN * kHD;         // 2944 elements per (hb,t) tile

typedef __attribute__((ext_vector_type(8))) short bf16x8;
typedef __attribute__((ext_vector_type(4))) float f32x4;

union FragU {
  bf16x8 f;
  ull u[2];
  uint4 q;
  u16 h[8];
};

#define MFMA(a, b, c) __builtin_amdgcn_mfma_f32_16x16x32_bf16((a), (b), (c), 0, 0, 0)

__device__ __forceinline__ float bf2f(u16 v) {
  return __uint_as_float(((u32)v) << 16);
}
__device__ __forceinline__ u16 f2bf(float f) {
  u32 x = __float_as_uint(f);
  x += 0x7fffu + ((x >> 16) & 1u);   // RNE
  return (u16)(x >> 16);
}
// pack two fp32 -> two bf16 (RNE) in one u32: lo in [15:0], hi in [31:16]
__device__ __forceinline__ u32 pack_bf2(float lo, float hi) {
  u32 a = __float_as_uint(lo); a += 0x7fffu + ((a >> 16) & 1u);
  u32 b = __float_as_uint(hi); b += 0x7fffu + ((b >> 16) & 1u);
  return __builtin_amdgcn_perm(b, a, 0x07060302);
}

// A/B fragment from row-major [192][16] bf16 tile store (stride 20 u16).
__device__ __forceinline__ bf16x8 ld_qk_frag(const u16* s, int tile, int lane) {
  FragU f;
  f.u[0] = 0; f.u[1] = 0;
  const int quad = lane >> 4;
  if (quad < 2) {
    const ull* p = (const ull*)(s + (tile * 16 + (lane & 15)) * 20 + quad * 8);
    f.u[0] = p[0];
    f.u[1] = p[1];
  }
  return f.f;
}

// ---------------------------------------------------------------------------
// Kernel 0: weights fp32 -> bf16 once. wb layout: [Wq|Wk|Wv|Wo], 16384 each.
// ---------------------------------------------------------------------------
__global__ __launch_bounds__(256) void wcvt_kernel(
    const float* __restrict__ Wq, const float* __restrict__ Wk,
    const float* __restrict__ Wv, const float* __restrict__ Wo,
    u16* __restrict__ wb) {
  const int t = blockIdx.x * 256 + threadIdx.x;   // 8192 threads, 2 elems each
  if (t >= 8192) return;
  u32* dst = (u32*)wb;
  float2 a = ((const float2*)Wq)[t]; dst[t]          = pack_bf2(a.x, a.y);
  float2 b = ((const float2*)Wk)[t]; dst[8192 + t]   = pack_bf2(b.x, b.y);
  float2 c = ((const float2*)Wv)[t]; dst[16384 + t]  = pack_bf2(c.x, c.y);
  float2 d = ((const float2*)Wo)[t]; dst[24576 + t]  = pack_bf2(d.x, d.y);
}

// ---------------------------------------------------------------------------
// Kernel 1: adp softmax fragments (unchanged from r3).
// ---------------------------------------------------------------------------
__global__ __launch_bounds__(256) void adp_kernel(
    const float* __restrict__ ne1, const float* __restrict__ ne2,
    u16* __restrict__ arr3, u16* __restrict__ arr4) {
  __shared__ float s1[kN * 10];
  __shared__ float s2[10 * kN];
  __shared__ float l1r[kN];
  __shared__ float l2c[kN];
  const int tid = threadIdx.x;
  for (int i = tid; i < kN * 10; i += 256) { s1[i] = ne1[i]; s2[i] = ne2[i]; }
  __syncthreads();

  if (tid < kN) {
    const int r = tid;
    float reg[10];
#pragma unroll
    for (int e = 0; e < 10; ++e) reg[e] = s1[r * 10 + e];
    float sum = 0.f;
    for (int c = 0; c < kN; ++c) {
      float d = 0.f;
#pragma unroll
      for (int e = 0; e < 10; ++e) d += reg[e] * s2[e * kN + c];
      sum += __expf(d);
    }
    l1r[r] = sum;

    const int c = tid;
    float regc[10];
#pragma unroll
    for (int e = 0; e < 10; ++e) regc[e] = s2[e * kN + c];
    sum = 0.f;
    for (int r2 = 0; r2 < kN; ++r2) {
      float d = 0.f;
#pragma unroll
      for (int e = 0; e < 10; ++e) d += s1[r2 * 10 + e] * regc[e];
      sum += __expf(d);
    }
    l2c[c] = sum;
  }
  __syncthreads();

  for (int ee = tid; ee < 12 * 6 * 64; ee += 256) {
    const int i = ee / 384;
    const int rem = ee - i * 384;
    const int p = rem >> 6;
    const int lane = rem & 63;
    const int row = i * 16 + (lane & 15);
    const int cb = p * 32 + (lane >> 4) * 8;
    FragU fo3, fo4;
    const bool rok = row < kN;
    float inv1 = 0.f, inv2 = 0.f;
    float rreg[10], creg[10];
    if (rok) {
      inv1 = 1.f / l1r[row];
      inv2 = 1.f / l2c[row];
#pragma unroll
      for (int e = 0; e < 10; ++e) {
        rreg[e] = s1[row * 10 + e];
        creg[e] = s2[e * kN + row];
      }
    }
#pragma unroll
    for (int j = 0; j < 8; ++j) {
      const int col = cb + j;
      float v3 = 0.f, v4 = 0.f;
      if (rok && col < kN) {
        float d3 = 0.f, d4 = 0.f;
#pragma unroll
        for (int e = 0; e < 10; ++e) {
          d3 += rreg[e] * s2[e * kN + col];
          d4 += s1[col * 10 + e] * creg[e];
        }
        v3 = __expf(d3) * inv1;
        v4 = __expf(d4) * inv2;
      }
      fo3.h[j] = f2bf(v3);
      fo4.h[j] = f2bf(v4);
    }
    *(uint4*)(arr3 + (size_t)ee * 8) = fo3.q;
    *(uint4*)(arr4 + (size_t)ee * 8) = fo4.q;
  }
}

// ---------------------------------------------------------------------------
// Kernel 2: MFMA projection GEMM. C[47104x128] = X @ W^T + b, bf16 split-head
// out. Block = 128 rows x 128 cols; wave w owns row-tiles {w, w+4}.
// A: fp32 from global, packed to bf16 in-register. B: bf16 W staged in LDS
// (stride 136 u16 -> 2-way conflicts only = free). 2 MFMAs per B-read.
// ---------------------------------------------------------------------------
__global__ __launch_bounds__(256) void proj_kernel(
    const float* __restrict__ qin, const float* __restrict__ kin, const float* __restrict__ vin,
    const u16* __restrict__ wb,
    const float* __restrict__ bq, const float* __restrict__ bk, const float* __restrict__ bv,
    u16* __restrict__ qo, u16* __restrict__ ko, u16* __restrict__ vo) {
  __shared__ u16 s_w[128 * 136];

  const float* in; const u16* W; const float* bias; u16* out;
  if (blockIdx.y == 0)      { in = qin; W = wb;         bias = bq; out = qo; }
  else if (blockIdx.y == 1) { in = kin; W = wb + 16384; bias = bk; out = ko; }
  else                      { in = vin; W = wb + 32768; bias = bv; out = vo; }

  const int tid = threadIdx.x;
  {
    const uint4* src = (const uint4*)W;
    for (int i = tid; i < 2048; i += 256) {
      const int row = i >> 4, q16 = i & 15;
      *(uint4*)(s_w + row * 136 + q16 * 8) = src[i];
    }
  }
  __syncthreads();

  const int w = tid >> 6, lane = tid & 63, quad = lane >> 4, m = lane & 15;
  const int r0 = blockIdx.x * 128;

  f32x4 acc0[8], acc1[8];
  const f32x4 z4 = {0.f, 0.f, 0.f, 0.f};
#pragma unroll
  for (int ct = 0; ct < 8; ++ct) { acc0[ct] = z4; acc1[ct] = z4; }

  const float* xp0 = in + (size_t)(r0 + w * 16 + m) * 128 + quad * 8;
  const float* xp1 = xp0 + 64 * 128;

#pragma unroll
  for (int kp = 0; kp < 4; ++kp) {
    const float4 xa = *(const float4*)(xp0 + kp * 32);
    const float4 xb = *(const float4*)(xp0 + kp * 32 + 4);
    const float4 ya = *(const float4*)(xp1 + kp * 32);
    const float4 yb = *(const float4*)(xp1 + kp * 32 + 4);
    FragU a0, a1;
    a0.q = make_uint4(pack_bf2(xa.x, xa.y), pack_bf2(xa.z, xa.w),
                      pack_bf2(xb.x, xb.y), pack_bf2(xb.z, xb.w));
    a1.q = make_uint4(pack_bf2(ya.x, ya.y), pack_bf2(ya.z, ya.w),
                      pack_bf2(yb.x, yb.y), pack_bf2(yb.z, yb.w));
#pragma unroll
    for (int ct = 0; ct < 8; ++ct) {
      FragU bfr; bfr.q = *(const uint4*)(s_w + (ct * 16 + m) * 136 + kp * 32 + quad * 8);
      acc0[ct] = MFMA(a0.f, bfr.f, acc0[ct]);
      acc1[ct] = MFMA(a1.f, bfr.f, acc1[ct]);
    }
  }

  float bc[8];
#pragma unroll
  for (int ct = 0; ct < 8; ++ct) bc[ct] = bias[ct * 16 + m];

#pragma unroll
  for (int half = 0; half < 2; ++half) {
    const f32x4* acc = half ? acc1 : acc0;
    const int rbase = r0 + (w + half * 4) * 16 + quad * 4;
#pragma unroll
    for (int rr = 0; rr < 4; ++rr) {
      const int r = rbase + rr;
      const int bt = r / kN;
      const int n = r - bt * kN;
      u16* op = out + ((size_t)bt * kN + n) * 16 + m;
#pragma unroll
      for (int ct = 0; ct < 8; ++ct)
        op[(size_t)ct * kBT * kN * 16] = f2bf(acc[ct][rr] + bc[ct]);
    }
  }
}

// ---------------------------------------------------------------------------
// Kernel 3: MFMA dual-softmax attention + adp mixing + fused Wm (unchanged r3).
// ---------------------------------------------------------------------------
__global__ __launch_bounds__(256) void attn_kernel(
    const u16* qg, const u16* __restrict__ kg, const u16* __restrict__ vg,
    const u16* __restrict__ arr3, const u16* __restrict__ arr4,
    const float* __restrict__ Wm, const float* __restrict__ bm,
    u16* mg) {
  __shared__ u16 s_q[192 * 20];
  __shared__ u16 s_k[192 * 20];
  __shared__ u16 s_vT[16 * 200];
  __shared__ u16 s_stage[4 * 640];
  __shared__ u16 s_cat[4 * 1152];

  const int tid = threadIdx.x;
  const size_t base = (size_t)blockIdx.x * kTile;

  for (int idx8 = tid; idx8 < 384; idx8 += 256) {
    const int t = idx8 >> 1, c0 = (idx8 & 1) * 8;
    ull zq0 = 0, zq1 = 0, zk0 = 0, zk1 = 0;
    if (t < kN) {
      const ull* qp = (const ull*)(qg + base + t * 16 + c0);
      const ull* kp = (const ull*)(kg + base + t * 16 + c0);
      zq0 = qp[0]; zq1 = qp[1];
      zk0 = kp[0]; zk1 = kp[1];
    }
    ull* dq = (ull*)(s_q + t * 20 + c0);
    ull* dk = (ull*)(s_k + t * 20 + c0);
    dq[0] = zq0; dq[1] = zq1;
    dk[0] = zk0; dk[1] = zk1;
  }
  for (int idx = tid; idx < 3072; idx += 256) {
    const int t = idx >> 4, ch = idx & 15;
    s_vT[ch * 200 + t] = (t < kN) ? vg[base + idx] : (u16)0;
  }
  __syncthreads();

  const int w = tid >> 6, lane = tid & 63;
  const int quad = lane >> 4, m = lane & 15;

  bf16x8 vb[6];
#pragma unroll
  for (int p = 0; p < 6; ++p) {
    FragU f;
    f.q = *(const uint4*)(s_vT + m * 200 + p * 32 + quad * 8);
    vb[p] = f.f;
  }
  FragU onesU; onesU.u[0] = 0x3F803F803F803F80ULL; onesU.u[1] = onesU.u[0];
  const bf16x8 ones = onesU.f;

  bf16x8 wmb[2];
#pragma unroll
  for (int kt = 0; kt < 2; ++kt) {
    const float* wp = Wm + m * 64 + kt * 32 + quad * 8;
    FragU f;
#pragma unroll
    for (int j = 0; j < 8; ++j) f.h[j] = f2bf(wp[j]);
    wmb[kt] = f.f;
  }
  const float bmv = bm[m];

  u16* stg = s_stage + w * 640;
  u16* cw = s_cat + w * 1152;
  const f32x4 zero4 = {0.f, 0.f, 0.f, 0.f};

  for (int tt = w; tt < 12; tt += 4) {
    f32x4 o1 = zero4, l1 = zero4, o3 = zero4, o4 = zero4;
    const bf16x8 qf = ld_qk_frag(s_q, tt, lane);
#pragma unroll
    for (int p = 0; p < 6; ++p) {
#pragma unroll
      for (int h = 0; h < 2; ++h) {
        const int k = p * 2 + h;
        const bf16x8 kf = ld_qk_frag(s_k, k, lane);
        f32x4 sv = MFMA(qf, kf, zero4);
        const bool kill = (k == 11) && (m >= 8);
#pragma unroll
        for (int r = 0; r < 4; ++r) {
          const float ev = kill ? 0.f : __expf(sv[r] * 0.25f);
          stg[(quad * 4 + r) * 40 + h * 16 + m] = f2bf(ev);
        }
      }
      FragU pa; pa.q = *(const uint4*)(stg + m * 40 + quad * 8);
      o1 = MFMA(pa.f, vb[p], o1);
      l1 = MFMA(pa.f, ones, l1);
      FragU a3; a3.q = *(const uint4*)(arr3 + (size_t)((tt * 6 + p) * 64 + lane) * 8);
      FragU a4; a4.q = *(const uint4*)(arr4 + (size_t)((tt * 6 + p) * 64 + lane) * 8);
      o3 = MFMA(a3.f, vb[p], o3);
      o4 = MFMA(a4.f, vb[p], o4);
    }
    f32x4 o2 = zero4, l2 = zero4;
    const bf16x8 kfc = ld_qk_frag(s_k, tt, lane);
#pragma unroll
    for (int p = 0; p < 6; ++p) {
#pragma unroll
      for (int h = 0; h < 2; ++h) {
        const int r = p * 2 + h;
        const bf16x8 qf2 = ld_qk_frag(s_q, r, lane);
        f32x4 sv = MFMA(qf2, kfc, zero4);
        const bool kill = (r == 11) && (quad >= 2);
#pragma unroll
        for (int rr = 0; rr < 4; ++rr) {
          const float ev = kill ? 0.f : __expf(sv[rr] * 0.25f);
          stg[m * 40 + h * 16 + quad * 4 + rr] = f2bf(ev);
        }
      }
      FragU pa; pa.q = *(const uint4*)(stg + m * 40 + quad * 8);
      o2 = MFMA(pa.f, vb[p], o2);
      l2 = MFMA(pa.f, ones, l2);
    }
#pragma unroll
    for (int r = 0; r < 4; ++r) {
      const int rowbase = (quad * 4 + r) * 72;
      cw[rowbase + m]      = f2bf(o1[r] / l1[r]);
      cw[rowbase + 16 + m] = f2bf(o2[r] / l2[r]);
      cw[rowbase + 32 + m] = f2bf(o3[r]);
      cw[rowbase + 48 + m] = f2bf(o4[r]);
    }
    f32x4 macc = {bmv, bmv, bmv, bmv};
#pragma unroll
    for (int kt = 0; kt < 2; ++kt) {
      FragU ca; ca.q = *(const uint4*)(cw + m * 72 + kt * 32 + quad * 8);
      macc = MFMA(ca.f, wmb[kt], macc);
    }
#pragma unroll
    for (int r = 0; r < 4; ++r) {
      const int row = tt * 16 + quad * 4 + r;
      if (row < kN) mg[base + row * 16 + m] = f2bf(macc[r]);
    }
  }
}

// ---------------------------------------------------------------------------
// Kernel 4: MFMA head-merge + Wo GEMM, fp32 out + bo.
// A-frags gathered from split-head m (8 consecutive hd = one dwordx4).
// ---------------------------------------------------------------------------
__global__ __launch_bounds__(256) void out_kernel(
    const u16* __restrict__ mg, const u16* __restrict__ wob,
    const float* __restrict__ bo, float* __restrict__ outg) {
  __shared__ u16 s_w[128 * 136];
  const int tid = threadIdx.x;
  {
    const uint4* src = (const uint4*)wob;
    for (int i = tid; i < 2048; i += 256) {
      const int row = i >> 4, q16 = i & 15;
      *(uint4*)(s_w + row * 136 + q16 * 8) = src[i];
    }
  }
  __syncthreads();

  const int w = tid >> 6, lane = tid & 63, quad = lane >> 4, m = lane & 15;
  const int r0 = blockIdx.x * 128;

  f32x4 acc0[8], acc1[8];
  const f32x4 z4 = {0.f, 0.f, 0.f, 0.f};
#pragma unroll
  for (int ct = 0; ct < 8; ++ct) { acc0[ct] = z4; acc1[ct] = z4; }

  const int hh = quad >> 1, hd8 = (quad & 1) * 8;
  const int ra = r0 + w * 16 + m;
  const int bt0 = ra / kN, n0 = ra - bt0 * kN;
  const int rb = ra + 64;
  const int bt1 = rb / kN, n1 = rb - bt1 * kN;
  const u16* mp0 = mg + ((size_t)(hh * kBT + bt0) * kN + n0) * 16 + hd8;
  const u16* mp1 = mg + ((size_t)(hh * kBT + bt1) * kN + n1) * 16 + hd8;
  const size_t hstep = (size_t)2 * kBT * kN * 16;   // kp -> h advances by 2

#pragma unroll
  for (int kp = 0; kp < 4; ++kp) {
    FragU a0; a0.q = *(const uint4*)(mp0 + kp * hstep);
    FragU a1; a1.q = *(const uint4*)(mp1 + kp * hstep);
#pragma unroll
    for (int ct = 0; ct < 8; ++ct) {
      FragU bfr; bfr.q = *(const uint4*)(s_w + (ct * 16 + m) * 136 + kp * 32 + quad * 8);
      acc0[ct] = MFMA(a0.f, bfr.f, acc0[ct]);
      acc1[ct] = MFMA(a1.f, bfr.f, acc1[ct]);
    }
  }

  float bc[8];
#pragma unroll
  for (int ct = 0; ct < 8; ++ct) bc[ct] = bo[ct * 16 + m];

#pragma unroll
  for (int half = 0; half < 2; ++half) {
    const f32x4* acc = half ? acc1 : acc0;
    const int rbase = r0 + (w + half * 4) * 16 + quad * 4;
#pragma unroll
    for (int rr = 0; rr < 4; ++rr) {
      float* op = outg + (size_t)(rbase + rr) * 128 + m;
#pragma unroll
      for (int ct = 0; ct < 8; ++ct)
        op[ct * 16] = acc[ct][rr] + bc[ct];
    }
  }
}

// ---------------------------------------------------------------------------
extern "C" void kernel_launch(void* const* d_in, const int* in_sizes, int n_in,
                              void* d_out, int out_size, void* d_ws, size_t ws_size,
                              hipStream_t stream) {
  const float* query = (const float*)d_in[0];
  const float* key   = (const float*)d_in[1];
  const float* value = (const float*)d_in[2];
  const float* Wq = (const float*)d_in[3];
  const float* bq = (const float*)d_in[4];
  const float* Wk = (const float*)d_in[5];
  const float* bk = (const float*)d_in[6];
  const float* Wv = (const float*)d_in[7];
  const float* bv = (const float*)d_in[8];
  const float* Wm = (const float*)d_in[9];
  const float* bm = (const float*)d_in[10];
  const float* Wo = (const float*)d_in[11];
  const float* bo = (const float*)d_in[12];
  const float* ne1 = (const float*)d_in[13];
  const float* ne2 = (const float*)d_in[14];

  const size_t tensor_bytes = (size_t)kH * kB * kT * kN * kHD * 2;  // 12,058,624
  const size_t frag_bytes = (size_t)12 * 6 * 64 * 8 * 2;            // 73,728
  char* ws = (char*)d_ws;
  u16* qs   = (u16*)(ws);                        // reused as m after attn
  u16* ks   = (u16*)(ws + tensor_bytes);
  u16* vs   = (u16*)(ws + 2 * tensor_bytes);
  u16* arr3 = (u16*)(ws + 3 * tensor_bytes);
  u16* arr4 = (u16*)(ws + 3 * tensor_bytes + frag_bytes);
  u16* wb   = (u16*)(ws + 3 * tensor_bytes + 2 * frag_bytes);  // 4x16384 bf16
  // total: ~36.5 MB + 128 KB

  wcvt_kernel<<<32, 256, 0, stream>>>(Wq, Wk, Wv, Wo, wb);
  adp_kernel<<<1, 256, 0, stream>>>(ne1, ne2, arr3, arr4);
  proj_kernel<<<dim3(kRows / 128, 3), 256, 0, stream>>>(
      query, key, value, wb, bq, bk, bv, qs, ks, vs);
  attn_kernel<<<kH * kB * kT, 256, 0, stream>>>(qs, ks, vs, arr3, arr4, Wm, bm, qs);
  out_kernel<<<kRows / 128, 256, 0, stream>>>(qs, wb + 49152, bo, (float*)d_out);
}

// Round 6
// 281.621 us; speedup vs baseline: 2.5498x; 1.0106x over previous
//
#include <hip/hip_runtime.h>

typedef unsigned int u32;
typedef unsigned short u16;
typedef unsigned long long ull;

constexpr int kB = 16, kT = 16, kN = 184, kD = 128, kH = 8, kHD = 16;
constexpr int kBT = kB * kT;            // 256
constexpr int kRows = kBT * kN;         // 47104
constexpr int kTile = kN * kHD;         // 2944 elements per (hb,t) tile
// softmax scale folded into q at projection: 0.25 * log2(e)
#define KQSCALE 0.36067376022224085f

typedef __attribute__((ext_vector_type(8))) short bf16x8;
typedef __attribute__((ext_vector_type(4))) float f32x4;

union FragU {
  bf16x8 f;
  ull u[2];
  uint4 q;
  u16 h[8];
};

#define MFMA(a, b, c) __builtin_amdgcn_mfma_f32_16x16x32_bf16((a), (b), (c), 0, 0, 0)

__device__ __forceinline__ float bf2f(u16 v) {
  return __uint_as_float(((u32)v) << 16);
}
__device__ __forceinline__ u16 f2bf(float f) {
  u32 x = __float_as_uint(f);
  x += 0x7fffu + ((x >> 16) & 1u);   // RNE
  return (u16)(x >> 16);
}
// pack two fp32 -> two bf16 (RNE) in one u32: lo in [15:0], hi in [31:16]
__device__ __forceinline__ u32 pack_bf2(float lo, float hi) {
  u32 a = __float_as_uint(lo); a += 0x7fffu + ((a >> 16) & 1u);
  u32 b = __float_as_uint(hi); b += 0x7fffu + ((b >> 16) & 1u);
  return __builtin_amdgcn_perm(b, a, 0x07060302);
}
// pack two fp32 -> two bf16 (truncate) in one u32 — single v_perm
__device__ __forceinline__ u32 pack_trunc(float lo, float hi) {
  return __builtin_amdgcn_perm(__float_as_uint(hi), __float_as_uint(lo), 0x07060302);
}

// one unconditional b128 fragment load from a [12*16][32] tile store
// (cols 16..31 are zero -> upper-K halves of A/B operands are zero)
__device__ __forceinline__ bf16x8 ld_frag(const u16* s, int tile, int m, int quad) {
  FragU f;
  f.q = *(const uint4*)(s + (tile * 16 + m) * 32 + quad * 8);
  return f.f;
}

// ---------------------------------------------------------------------------
// Kernel 0: weights fp32 -> bf16 once. wb layout: [Wq|Wk|Wv|Wo], 16384 each.
// ---------------------------------------------------------------------------
__global__ __launch_bounds__(256) void wcvt_kernel(
    const float* __restrict__ Wq, const float* __restrict__ Wk,
    const float* __restrict__ Wv, const float* __restrict__ Wo,
    u16* __restrict__ wb) {
  const int t = blockIdx.x * 256 + threadIdx.x;   // 8192 threads, 2 elems each
  if (t >= 8192) return;
  u32* dst = (u32*)wb;
  float2 a = ((const float2*)Wq)[t]; dst[t]          = pack_bf2(a.x, a.y);
  float2 b = ((const float2*)Wk)[t]; dst[8192 + t]   = pack_bf2(b.x, b.y);
  float2 c = ((const float2*)Wv)[t]; dst[16384 + t]  = pack_bf2(c.x, c.y);
  float2 d = ((const float2*)Wo)[t]; dst[24576 + t]  = pack_bf2(d.x, d.y);
}

// ---------------------------------------------------------------------------
// Kernel 1: adp softmax fragments (unchanged).
// ---------------------------------------------------------------------------
__global__ __launch_bounds__(256) void adp_kernel(
    const float* __restrict__ ne1, const float* __restrict__ ne2,
    u16* __restrict__ arr3, u16* __restrict__ arr4) {
  __shared__ float s1[kN * 10];
  __shared__ float s2[10 * kN];
  __shared__ float l1r[kN];
  __shared__ float l2c[kN];
  const int tid = threadIdx.x;
  for (int i = tid; i < kN * 10; i += 256) { s1[i] = ne1[i]; s2[i] = ne2[i]; }
  __syncthreads();

  if (tid < kN) {
    const int r = tid;
    float reg[10];
#pragma unroll
    for (int e = 0; e < 10; ++e) reg[e] = s1[r * 10 + e];
    float sum = 0.f;
    for (int c = 0; c < kN; ++c) {
      float d = 0.f;
#pragma unroll
      for (int e = 0; e < 10; ++e) d += reg[e] * s2[e * kN + c];
      sum += __expf(d);
    }
    l1r[r] = sum;

    const int c = tid;
    float regc[10];
#pragma unroll
    for (int e = 0; e < 10; ++e) regc[e] = s2[e * kN + c];
    sum = 0.f;
    for (int r2 = 0; r2 < kN; ++r2) {
      float d = 0.f;
#pragma unroll
      for (int e = 0; e < 10; ++e) d += s1[r2 * 10 + e] * regc[e];
      sum += __expf(d);
    }
    l2c[c] = sum;
  }
  __syncthreads();

  for (int ee = tid; ee < 12 * 6 * 64; ee += 256) {
    const int i = ee / 384;
    const int rem = ee - i * 384;
    const int p = rem >> 6;
    const int lane = rem & 63;
    const int row = i * 16 + (lane & 15);
    const int cb = p * 32 + (lane >> 4) * 8;
    FragU fo3, fo4;
    const bool rok = row < kN;
    float inv1 = 0.f, inv2 = 0.f;
    float rreg[10], creg[10];
    if (rok) {
      inv1 = 1.f / l1r[row];
      inv2 = 1.f / l2c[row];
#pragma unroll
      for (int e = 0; e < 10; ++e) {
        rreg[e] = s1[row * 10 + e];
        creg[e] = s2[e * kN + row];
      }
    }
#pragma unroll
    for (int j = 0; j < 8; ++j) {
      const int col = cb + j;
      float v3 = 0.f, v4 = 0.f;
      if (rok && col < kN) {
        float d3 = 0.f, d4 = 0.f;
#pragma unroll
        for (int e = 0; e < 10; ++e) {
          d3 += rreg[e] * s2[e * kN + col];
          d4 += s1[col * 10 + e] * creg[e];
        }
        v3 = __expf(d3) * inv1;
        v4 = __expf(d4) * inv2;
      }
      fo3.h[j] = f2bf(v3);
      fo4.h[j] = f2bf(v4);
    }
    *(uint4*)(arr3 + (size_t)ee * 8) = fo3.q;
    *(uint4*)(arr4 + (size_t)ee * 8) = fo4.q;
  }
}

// ---------------------------------------------------------------------------
// Kernel 2: MFMA projection GEMM. q output pre-scaled by 0.25*log2(e) so the
// attention kernel's exp is a bare v_exp_f32 (exp2).
// ---------------------------------------------------------------------------
__global__ __launch_bounds__(256) void proj_kernel(
    const float* __restrict__ qin, const float* __restrict__ kin, const float* __restrict__ vin,
    const u16* __restrict__ wb,
    const float* __restrict__ bq, const float* __restrict__ bk, const float* __restrict__ bv,
    u16* __restrict__ qo, u16* __restrict__ ko, u16* __restrict__ vo) {
  __shared__ u16 s_w[128 * 136];

  const float* in; const u16* W; const float* bias; u16* out; float scale;
  if (blockIdx.y == 0)      { in = qin; W = wb;         bias = bq; out = qo; scale = KQSCALE; }
  else if (blockIdx.y == 1) { in = kin; W = wb + 16384; bias = bk; out = ko; scale = 1.f; }
  else                      { in = vin; W = wb + 32768; bias = bv; out = vo; scale = 1.f; }

  const int tid = threadIdx.x;
  {
    const uint4* src = (const uint4*)W;
    for (int i = tid; i < 2048; i += 256) {
      const int row = i >> 4, q16 = i & 15;
      *(uint4*)(s_w + row * 136 + q16 * 8) = src[i];
    }
  }
  __syncthreads();

  const int w = tid >> 6, lane = tid & 63, quad = lane >> 4, m = lane & 15;
  const int r0 = blockIdx.x * 128;

  f32x4 acc0[8], acc1[8];
  const f32x4 z4 = {0.f, 0.f, 0.f, 0.f};
#pragma unroll
  for (int ct = 0; ct < 8; ++ct) { acc0[ct] = z4; acc1[ct] = z4; }

  const float* xp0 = in + (size_t)(r0 + w * 16 + m) * 128 + quad * 8;
  const float* xp1 = xp0 + 64 * 128;

#pragma unroll
  for (int kp = 0; kp < 4; ++kp) {
    const float4 xa = *(const float4*)(xp0 + kp * 32);
    const float4 xb = *(const float4*)(xp0 + kp * 32 + 4);
    const float4 ya = *(const float4*)(xp1 + kp * 32);
    const float4 yb = *(const float4*)(xp1 + kp * 32 + 4);
    FragU a0, a1;
    a0.q = make_uint4(pack_bf2(xa.x, xa.y), pack_bf2(xa.z, xa.w),
                      pack_bf2(xb.x, xb.y), pack_bf2(xb.z, xb.w));
    a1.q = make_uint4(pack_bf2(ya.x, ya.y), pack_bf2(ya.z, ya.w),
                      pack_bf2(yb.x, yb.y), pack_bf2(yb.z, yb.w));
#pragma unroll
    for (int ct = 0; ct < 8; ++ct) {
      FragU bfr; bfr.q = *(const uint4*)(s_w + (ct * 16 + m) * 136 + kp * 32 + quad * 8);
      acc0[ct] = MFMA(a0.f, bfr.f, acc0[ct]);
      acc1[ct] = MFMA(a1.f, bfr.f, acc1[ct]);
    }
  }

  float bc[8];
#pragma unroll
  for (int ct = 0; ct < 8; ++ct) bc[ct] = bias[ct * 16 + m];

#pragma unroll
  for (int half = 0; half < 2; ++half) {
    const f32x4* acc = half ? acc1 : acc0;
    const int rbase = r0 + (w + half * 4) * 16 + quad * 4;
#pragma unroll
    for (int rr = 0; rr < 4; ++rr) {
      const int r = rbase + rr;
      const int bt = r / kN;
      const int n = r - bt * kN;
      u16* op = out + ((size_t)bt * kN + n) * 16 + m;
#pragma unroll
      for (int ct = 0; ct < 8; ++ct)
        op[(size_t)ct * kBT * kN * 16] = f2bf((acc[ct][rr] + bc[ct]) * scale);
    }
  }
}

// ---------------------------------------------------------------------------
// Kernel 3: MFMA dual-softmax attention + adp mixing + fused Wm.
// q pre-scaled -> E = exp2(S'). Pads staged as exact zeros -> E_pad = 1.0,
// V_pad = 0 -> only l1/l2 polluted by exactly +8.0, corrected pre-rcp.
// Row pass computes S^T (MFMA(kf,qf)) so both passes stage E with packed
// v_perm-trunc + ds_write_b32, then read back as b128 A-fragments.
// Epilogue: filt^T = MFMA(Wm_A, cat_B) -> packed dwordx2 global stores.
// mg aliases qg (tile fully read into LDS before any write).
// BUGFIX vs r5: q/k staging now copies the FULL 8-element half-row (uint4);
// r5's single-ull copy left LDS cols 4-7/12-15 (and half the zero pad)
// uninitialized -> garbage scores -> exp2 -> Inf -> Inf*rcp(Inf) = NaN.
// ---------------------------------------------------------------------------
__global__ __launch_bounds__(256, 3) void attn_kernel(
    const u16* qg, const u16* __restrict__ kg, const u16* __restrict__ vg,
    const u16* __restrict__ arr3, const u16* __restrict__ arr4,
    const float* __restrict__ Wm, const float* __restrict__ bm,
    u16* mg) {
  __shared__ u16 s_q[192 * 32];    // [token][32], cols 16..31 zero (K-pad)
  __shared__ u16 s_k[192 * 32];
  __shared__ u16 s_vT[16 * 200];   // [ch][token], zero-padded tokens
  __shared__ u16 s_stage[4 * 640]; // per-wave [16][40] E staging
  __shared__ u16 s_cat[4 * 1152];  // per-wave [16][72] cat staging

  const int tid = threadIdx.x;
  const size_t base = (size_t)blockIdx.x * kTile;

  const uint4 z16 = make_uint4(0, 0, 0, 0);
  for (int idx = tid; idx < 384; idx += 256) {
    const int t = idx >> 1, c0 = (idx & 1) * 8;
    uint4 zq = z16, zk = z16;
    if (t < kN) {
      zq = *(const uint4*)(qg + base + t * 16 + c0);
      zk = *(const uint4*)(kg + base + t * 16 + c0);
    }
    *(uint4*)(s_q + t * 32 + c0) = zq;
    *(uint4*)(s_q + t * 32 + 16 + c0) = z16;
    *(uint4*)(s_k + t * 32 + c0) = zk;
    *(uint4*)(s_k + t * 32 + 16 + c0) = z16;
  }
  for (int idx = tid; idx < 3072; idx += 256) {
    const int t = idx >> 4, ch = idx & 15;
    s_vT[ch * 200 + t] = (t < kN) ? vg[base + idx] : (u16)0;
  }
  __syncthreads();

  const int w = tid >> 6, lane = tid & 63;
  const int quad = lane >> 4, m = lane & 15;

  bf16x8 vb[6];   // V B-frags: B[kd][n] = V[32p+kd][n]
#pragma unroll
  for (int p = 0; p < 6; ++p) {
    FragU f;
    f.q = *(const uint4*)(s_vT + m * 200 + p * 32 + quad * 8);
    vb[p] = f.f;
  }
  FragU onesU; onesU.u[0] = 0x3F803F803F803F80ULL; onesU.u[1] = onesU.u[0];
  const bf16x8 ones = onesU.f;

  bf16x8 wmb[2];  // Wm rows (A-operand): A[m][kd] = Wm[m][kt*32+kd]
#pragma unroll
  for (int kt = 0; kt < 2; ++kt) {
    const float* wp = Wm + m * 64 + kt * 32 + quad * 8;
    FragU f;
#pragma unroll
    for (int j = 0; j < 8; ++j) f.h[j] = f2bf(wp[j]);
    wmb[kt] = f.f;
  }
  const float4 bm4 = *(const float4*)(bm + quad * 4);  // bias for chans quad*4+r

  u16* stg = s_stage + w * 640;
  u16* cw = s_cat + w * 1152;
  u16* stgw = stg + m * 40 + quad * 4;        // packed E write base (+h*16, +0/2)
  const u16* stgr = stg + m * 40 + quad * 8;  // b128 E read base
  const f32x4 zero4 = {0.f, 0.f, 0.f, 0.f};

  for (int tt = w; tt < 12; tt += 4) {
    // ================= row pass (q-tile = tt) =================
    f32x4 o1 = zero4, l1 = zero4, o3 = zero4, o4 = zero4;
    const bf16x8 qB = ld_frag(s_q, tt, m, quad);   // B-op: Q_tt^T
#pragma unroll
    for (int p = 0; p < 6; ++p) {
#pragma unroll
      for (int h = 0; h < 2; ++h) {
        const bf16x8 kA = ld_frag(s_k, p * 2 + h, m, quad);  // A-op: K tile
        f32x4 sv = MFMA(kA, qB, zero4);   // S^T: row=token(quad*4+r), col=qrow m
        *(u32*)(stgw + h * 16)     = pack_trunc(exp2f(sv[0]), exp2f(sv[1]));
        *(u32*)(stgw + h * 16 + 2) = pack_trunc(exp2f(sv[2]), exp2f(sv[3]));
      }
      FragU pa; pa.q = *(const uint4*)stgr;   // A = E_pair[qrow][token]
      o1 = MFMA(pa.f, vb[p], o1);
      l1 = MFMA(pa.f, ones, l1);
      FragU a3; a3.q = *(const uint4*)(arr3 + (size_t)((tt * 6 + p) * 64 + lane) * 8);
      FragU a4; a4.q = *(const uint4*)(arr4 + (size_t)((tt * 6 + p) * 64 + lane) * 8);
      o3 = MFMA(a3.f, vb[p], o3);
      o4 = MFMA(a4.f, vb[p], o4);
    }
    // ================= col pass (k-tile = tt) =================
    f32x4 o2 = zero4, l2 = zero4;
    const bf16x8 kB = ld_frag(s_k, tt, m, quad);   // B-op: K_tt^T
#pragma unroll
    for (int p = 0; p < 6; ++p) {
#pragma unroll
      for (int h = 0; h < 2; ++h) {
        const bf16x8 qA = ld_frag(s_q, p * 2 + h, m, quad);  // A-op: Q tile
        f32x4 sv = MFMA(qA, kB, zero4);   // S: row=qrow(quad*4+r), col=kcol m
        *(u32*)(stgw + h * 16)     = pack_trunc(exp2f(sv[0]), exp2f(sv[1]));
        *(u32*)(stgw + h * 16 + 2) = pack_trunc(exp2f(sv[2]), exp2f(sv[3]));
      }
      FragU pa; pa.q = *(const uint4*)stgr;   // A = E^T[kcol][qrow]
      o2 = MFMA(pa.f, vb[p], o2);
      l2 = MFMA(pa.f, ones, l2);
    }
    // ================= fused Wm epilogue =================
#pragma unroll
    for (int r = 0; r < 4; ++r) {
      const int rowbase = (quad * 4 + r) * 72;
      cw[rowbase + m]      = f2bf(o1[r] * __builtin_amdgcn_rcpf(l1[r] - 8.0f));
      cw[rowbase + 16 + m] = f2bf(o2[r] * __builtin_amdgcn_rcpf(l2[r] - 8.0f));
      cw[rowbase + 32 + m] = f2bf(o3[r]);
      cw[rowbase + 48 + m] = f2bf(o4[r]);
    }
    f32x4 macc = {bm4.x, bm4.y, bm4.z, bm4.w};
#pragma unroll
    for (int kt = 0; kt < 2; ++kt) {
      FragU ca; ca.q = *(const uint4*)(cw + m * 72 + kt * 32 + quad * 8);
      macc = MFMA(wmb[kt], ca.f, macc);   // filt^T = Wm @ cat^T
    }
    // C: col=m -> token (tt*16+m), row=quad*4+r -> chan
    if (tt * 16 + m < kN) {
      const u32 p0 = pack_bf2(macc[0], macc[1]);
      const u32 p1 = pack_bf2(macc[2], macc[3]);
      *(uint2*)(mg + base + (tt * 16 + m) * 16 + quad * 4) = make_uint2(p0, p1);
    }
  }
}

// ---------------------------------------------------------------------------
// Kernel 4: MFMA head-merge + Wo GEMM, fp32 out + bo (unchanged).
// ---------------------------------------------------------------------------
__global__ __launch_bounds__(256) void out_kernel(
    const u16* __restrict__ mg, const u16* __restrict__ wob,
    const float* __restrict__ bo, float* __restrict__ outg) {
  __shared__ u16 s_w[128 * 136];
  const int tid = threadIdx.x;
  {
    const uint4* src = (const uint4*)wob;
    for (int i = tid; i < 2048; i += 256) {
      const int row = i >> 4, q16 = i & 15;
      *(uint4*)(s_w + row * 136 + q16 * 8) = src[i];
    }
  }
  __syncthreads();

  const int w = tid >> 6, lane = tid & 63, quad = lane >> 4, m = lane & 15;
  const int r0 = blockIdx.x * 128;

  f32x4 acc0[8], acc1[8];
  const f32x4 z4 = {0.f, 0.f, 0.f, 0.f};
#pragma unroll
  for (int ct = 0; ct < 8; ++ct) { acc0[ct] = z4; acc1[ct] = z4; }

  const int hh = quad >> 1, hd8 = (quad & 1) * 8;
  const int ra = r0 + w * 16 + m;
  const int bt0 = ra / kN, n0 = ra - bt0 * kN;
  const int rb = ra + 64;
  const int bt1 = rb / kN, n1 = rb - bt1 * kN;
  const u16* mp0 = mg + ((size_t)(hh * kBT + bt0) * kN + n0) * 16 + hd8;
  const u16* mp1 = mg + ((size_t)(hh * kBT + bt1) * kN + n1) * 16 + hd8;
  const size_t hstep = (size_t)2 * kBT * kN * 16;

#pragma unroll
  for (int kp = 0; kp < 4; ++kp) {
    FragU a0; a0.q = *(const uint4*)(mp0 + kp * hstep);
    FragU a1; a1.q = *(const uint4*)(mp1 + kp * hstep);
#pragma unroll
    for (int ct = 0; ct < 8; ++ct) {
      FragU bfr; bfr.q = *(const uint4*)(s_w + (ct * 16 + m) * 136 + kp * 32 + quad * 8);
      acc0[ct] = MFMA(a0.f, bfr.f, acc0[ct]);
      acc1[ct] = MFMA(a1.f, bfr.f, acc1[ct]);
    }
  }

  float bc[8];
#pragma unroll
  for (int ct = 0; ct < 8; ++ct) bc[ct] = bo[ct * 16 + m];

#pragma unroll
  for (int half = 0; half < 2; ++half) {
    const f32x4* acc = half ? acc1 : acc0;
    const int rbase = r0 + (w + half * 4) * 16 + quad * 4;
#pragma unroll
    for (int rr = 0; rr < 4; ++rr) {
      float* op = outg + (size_t)(rbase + rr) * 128 + m;
#pragma unroll
      for (int ct = 0; ct < 8; ++ct)
        op[ct * 16] = acc[ct][rr] + bc[ct];
    }
  }
}

// ---------------------------------------------------------------------------
extern "C" void kernel_launch(void* const* d_in, const int* in_sizes, int n_in,
                              void* d_out, int out_size, void* d_ws, size_t ws_size,
                              hipStream_t stream) {
  const float* query = (const float*)d_in[0];
  const float* key   = (const float*)d_in[1];
  const float* value = (const float*)d_in[2];
  const float* Wq = (const float*)d_in[3];
  const float* bq = (const float*)d_in[4];
  const float* Wk = (const float*)d_in[5];
  const float* bk = (const float*)d_in[6];
  const float* Wv = (const float*)d_in[7];
  const float* bv = (const float*)d_in[8];
  const float* Wm = (const float*)d_in[9];
  const float* bm = (const float*)d_in[10];
  const float* Wo = (const float*)d_in[11];
  const float* bo = (const float*)d_in[12];
  const float* ne1 = (const float*)d_in[13];
  const float* ne2 = (const float*)d_in[14];

  const size_t tensor_bytes = (size_t)kH * kB * kT * kN * kHD * 2;  // 12,058,624
  const size_t frag_bytes = (size_t)12 * 6 * 64 * 8 * 2;            // 73,728
  char* ws = (char*)d_ws;
  u16* qs   = (u16*)(ws);                        // reused as m after attn
  u16* ks   = (u16*)(ws + tensor_bytes);
  u16* vs   = (u16*)(ws + 2 * tensor_bytes);
  u16* arr3 = (u16*)(ws + 3 * tensor_bytes);
  u16* arr4 = (u16*)(ws + 3 * tensor_bytes + frag_bytes);
  u16* wb   = (u16*)(ws + 3 * tensor_bytes + 2 * frag_bytes);  // 4x16384 bf16

  wcvt_kernel<<<32, 256, 0, stream>>>(Wq, Wk, Wv, Wo, wb);
  adp_kernel<<<1, 256, 0, stream>>>(ne1, ne2, arr3, arr4);
  proj_kernel<<<dim3(kRows / 128, 3), 256, 0, stream>>>(
      query, key, value, wb, bq, bk, bv, qs, ks, vs);
  attn_kernel<<<kH * kB * kT, 256, 0, stream>>>(qs, ks, vs, arr3, arr4, Wm, bm, qs);
  out_kernel<<<kRows / 128, 256, 0, stream>>>(qs, wb + 49152, bo, (float*)d_out);
}

// Round 7
// 281.277 us; speedup vs baseline: 2.5529x; 1.0012x over previous
//
#include <hip/hip_runtime.h>

typedef unsigned int u32;
typedef unsigned short u16;
typedef unsigned long long ull;

constexpr int kB = 16, kT = 16, kN = 184, kD = 128, kH = 8, kHD = 16;
constexpr int kBT = kB * kT;            // 256
constexpr int kRows = kBT * kN;         // 47104
constexpr int kTile = kN * kHD;         // 2944 elements per (hb,t) tile
// softmax scale folded into q at projection: 0.25 * log2(e)
#define KQSCALE 0.36067376022224085f

typedef __attribute__((ext_vector_type(8))) short bf16x8;
typedef __attribute__((ext_vector_type(4))) float f32x4;

union FragU {
  bf16x8 f;
  ull u[2];
  uint4 q;
  u16 h[8];
};

#define MFMA(a, b, c) __builtin_amdgcn_mfma_f32_16x16x32_bf16((a), (b), (c), 0, 0, 0)

__device__ __forceinline__ float bf2f(u16 v) {
  return __uint_as_float(((u32)v) << 16);
}
__device__ __forceinline__ u16 f2bf(float f) {
  u32 x = __float_as_uint(f);
  x += 0x7fffu + ((x >> 16) & 1u);   // RNE
  return (u16)(x >> 16);
}
// pack two fp32 -> two bf16 (RNE) in one u32: lo in [15:0], hi in [31:16]
__device__ __forceinline__ u32 pack_bf2(float lo, float hi) {
  u32 a = __float_as_uint(lo); a += 0x7fffu + ((a >> 16) & 1u);
  u32 b = __float_as_uint(hi); b += 0x7fffu + ((b >> 16) & 1u);
  return __builtin_amdgcn_perm(b, a, 0x07060302);
}
// pack two fp32 -> two bf16 (truncate) in one u32 — single v_perm
__device__ __forceinline__ u32 pack_trunc(float lo, float hi) {
  return __builtin_amdgcn_perm(__float_as_uint(hi), __float_as_uint(lo), 0x07060302);
}

// ---------------------------------------------------------------------------
// Kernel 0: weights fp32 -> bf16 once. wb layout: [Wq|Wk|Wv|Wo], 16384 each.
// ---------------------------------------------------------------------------
__global__ __launch_bounds__(256) void wcvt_kernel(
    const float* __restrict__ Wq, const float* __restrict__ Wk,
    const float* __restrict__ Wv, const float* __restrict__ Wo,
    u16* __restrict__ wb) {
  const int t = blockIdx.x * 256 + threadIdx.x;   // 8192 threads, 2 elems each
  if (t >= 8192) return;
  u32* dst = (u32*)wb;
  float2 a = ((const float2*)Wq)[t]; dst[t]          = pack_bf2(a.x, a.y);
  float2 b = ((const float2*)Wk)[t]; dst[8192 + t]   = pack_bf2(b.x, b.y);
  float2 c = ((const float2*)Wv)[t]; dst[16384 + t]  = pack_bf2(c.x, c.y);
  float2 d = ((const float2*)Wo)[t]; dst[24576 + t]  = pack_bf2(d.x, d.y);
}

// ---------------------------------------------------------------------------
// Kernel 1: adp softmax fragments (unchanged).
// ---------------------------------------------------------------------------
__global__ __launch_bounds__(256) void adp_kernel(
    const float* __restrict__ ne1, const float* __restrict__ ne2,
    u16* __restrict__ arr3, u16* __restrict__ arr4) {
  __shared__ float s1[kN * 10];
  __shared__ float s2[10 * kN];
  __shared__ float l1r[kN];
  __shared__ float l2c[kN];
  const int tid = threadIdx.x;
  for (int i = tid; i < kN * 10; i += 256) { s1[i] = ne1[i]; s2[i] = ne2[i]; }
  __syncthreads();

  if (tid < kN) {
    const int r = tid;
    float reg[10];
#pragma unroll
    for (int e = 0; e < 10; ++e) reg[e] = s1[r * 10 + e];
    float sum = 0.f;
    for (int c = 0; c < kN; ++c) {
      float d = 0.f;
#pragma unroll
      for (int e = 0; e < 10; ++e) d += reg[e] * s2[e * kN + c];
      sum += __expf(d);
    }
    l1r[r] = sum;

    const int c = tid;
    float regc[10];
#pragma unroll
    for (int e = 0; e < 10; ++e) regc[e] = s2[e * kN + c];
    sum = 0.f;
    for (int r2 = 0; r2 < kN; ++r2) {
      float d = 0.f;
#pragma unroll
      for (int e = 0; e < 10; ++e) d += s1[r2 * 10 + e] * regc[e];
      sum += __expf(d);
    }
    l2c[c] = sum;
  }
  __syncthreads();

  for (int ee = tid; ee < 12 * 6 * 64; ee += 256) {
    const int i = ee / 384;
    const int rem = ee - i * 384;
    const int p = rem >> 6;
    const int lane = rem & 63;
    const int row = i * 16 + (lane & 15);
    const int cb = p * 32 + (lane >> 4) * 8;
    FragU fo3, fo4;
    const bool rok = row < kN;
    float inv1 = 0.f, inv2 = 0.f;
    float rreg[10], creg[10];
    if (rok) {
      inv1 = 1.f / l1r[row];
      inv2 = 1.f / l2c[row];
#pragma unroll
      for (int e = 0; e < 10; ++e) {
        rreg[e] = s1[row * 10 + e];
        creg[e] = s2[e * kN + row];
      }
    }
#pragma unroll
    for (int j = 0; j < 8; ++j) {
      const int col = cb + j;
      float v3 = 0.f, v4 = 0.f;
      if (rok && col < kN) {
        float d3 = 0.f, d4 = 0.f;
#pragma unroll
        for (int e = 0; e < 10; ++e) {
          d3 += rreg[e] * s2[e * kN + col];
          d4 += s1[col * 10 + e] * creg[e];
        }
        v3 = __expf(d3) * inv1;
        v4 = __expf(d4) * inv2;
      }
      fo3.h[j] = f2bf(v3);
      fo4.h[j] = f2bf(v4);
    }
    *(uint4*)(arr3 + (size_t)ee * 8) = fo3.q;
    *(uint4*)(arr4 + (size_t)ee * 8) = fo4.q;
  }
}

// ---------------------------------------------------------------------------
// Kernel 2: MFMA projection GEMM (unchanged from r6). q output pre-scaled.
// ---------------------------------------------------------------------------
__global__ __launch_bounds__(256) void proj_kernel(
    const float* __restrict__ qin, const float* __restrict__ kin, const float* __restrict__ vin,
    const u16* __restrict__ wb,
    const float* __restrict__ bq, const float* __restrict__ bk, const float* __restrict__ bv,
    u16* __restrict__ qo, u16* __restrict__ ko, u16* __restrict__ vo) {
  __shared__ u16 s_w[128 * 136];

  const float* in; const u16* W; const float* bias; u16* out; float scale;
  if (blockIdx.y == 0)      { in = qin; W = wb;         bias = bq; out = qo; scale = KQSCALE; }
  else if (blockIdx.y == 1) { in = kin; W = wb + 16384; bias = bk; out = ko; scale = 1.f; }
  else                      { in = vin; W = wb + 32768; bias = bv; out = vo; scale = 1.f; }

  const int tid = threadIdx.x;
  {
    const uint4* src = (const uint4*)W;
    for (int i = tid; i < 2048; i += 256) {
      const int row = i >> 4, q16 = i & 15;
      *(uint4*)(s_w + row * 136 + q16 * 8) = src[i];
    }
  }
  __syncthreads();

  const int w = tid >> 6, lane = tid & 63, quad = lane >> 4, m = lane & 15;
  const int r0 = blockIdx.x * 128;

  f32x4 acc0[8], acc1[8];
  const f32x4 z4 = {0.f, 0.f, 0.f, 0.f};
#pragma unroll
  for (int ct = 0; ct < 8; ++ct) { acc0[ct] = z4; acc1[ct] = z4; }

  const float* xp0 = in + (size_t)(r0 + w * 16 + m) * 128 + quad * 8;
  const float* xp1 = xp0 + 64 * 128;

#pragma unroll
  for (int kp = 0; kp < 4; ++kp) {
    const float4 xa = *(const float4*)(xp0 + kp * 32);
    const float4 xb = *(const float4*)(xp0 + kp * 32 + 4);
    const float4 ya = *(const float4*)(xp1 + kp * 32);
    const float4 yb = *(const float4*)(xp1 + kp * 32 + 4);
    FragU a0, a1;
    a0.q = make_uint4(pack_bf2(xa.x, xa.y), pack_bf2(xa.z, xa.w),
                      pack_bf2(xb.x, xb.y), pack_bf2(xb.z, xb.w));
    a1.q = make_uint4(pack_bf2(ya.x, ya.y), pack_bf2(ya.z, ya.w),
                      pack_bf2(yb.x, yb.y), pack_bf2(yb.z, yb.w));
#pragma unroll
    for (int ct = 0; ct < 8; ++ct) {
      FragU bfr; bfr.q = *(const uint4*)(s_w + (ct * 16 + m) * 136 + kp * 32 + quad * 8);
      acc0[ct] = MFMA(a0.f, bfr.f, acc0[ct]);
      acc1[ct] = MFMA(a1.f, bfr.f, acc1[ct]);
    }
  }

  float bc[8];
#pragma unroll
  for (int ct = 0; ct < 8; ++ct) bc[ct] = bias[ct * 16 + m];

#pragma unroll
  for (int half = 0; half < 2; ++half) {
    const f32x4* acc = half ? acc1 : acc0;
    const int rbase = r0 + (w + half * 4) * 16 + quad * 4;
#pragma unroll
    for (int rr = 0; rr < 4; ++rr) {
      const int r = rbase + rr;
      const int bt = r / kN;
      const int n = r - bt * kN;
      u16* op = out + ((size_t)bt * kN + n) * 16 + m;
#pragma unroll
      for (int ct = 0; ct < 8; ++ct)
        op[(size_t)ct * kBT * kN * 16] = f2bf((acc[ct][rr] + bc[ct]) * scale);
    }
  }
}

// ---------------------------------------------------------------------------
// Kernel 3: MFMA dual-softmax attention + adp mixing + fused Wm.
// r7 changes vs r6:
//  * q/k fragments live in REGISTERS, loaded straight from global (16B/lane,
//    quad<2, zero-padded) — no s_q/s_k LDS, no per-iteration frag ds_reads.
//    Static indexing only (p-loops unrolled); runtime-tt qB/kB operands are
//    re-loaded from global — they are this wave's OWN tiles (read before its
//    own aliased mg write; no cross-wave hazard).
//  * E staging: single ds_write_b64 per S-MFMA (2x v_perm trunc-pack).
//  * cat staging: interleaved dim order (o1/o2, o3/o4 channel pairs) ->
//    8 conflict-free ds_write_b32; wmb built against permuted dims.
// ---------------------------------------------------------------------------
__global__ __launch_bounds__(256, 2) void attn_kernel(
    const u16* qg, const u16* __restrict__ kg, const u16* __restrict__ vg,
    const u16* __restrict__ arr3, const u16* __restrict__ arr4,
    const float* __restrict__ Wm, const float* __restrict__ bm,
    u16* mg) {
  __shared__ u16 s_vT[16 * 200];   // [ch][token], zero-padded tokens
  __shared__ u16 s_stage[4 * 640]; // per-wave [16][40] E staging
  __shared__ u16 s_cat[4 * 1152];  // per-wave [16][72] cat staging

  const int tid = threadIdx.x;
  const size_t base = (size_t)blockIdx.x * kTile;
  const int w = tid >> 6, lane = tid & 63;
  const int quad = lane >> 4, m = lane & 15;

  // ---- stage V transposed into LDS
  for (int idx = tid; idx < 3072; idx += 256) {
    const int t = idx >> 4, ch = idx & 15;
    s_vT[ch * 200 + t] = (t < kN) ? vg[base + idx] : (u16)0;
  }

  // ---- preload ALL 12 q- and k-tile fragments direct from global.
  // frag layout == A and B operand layout: lane(m,quad<2) holds
  // tile[token=t12*16+m][ch=quad*8..+7]; quads 2,3 (K-pad) and pad tokens = 0.
  bf16x8 qfr[12], kfr[12];
#pragma unroll
  for (int t12 = 0; t12 < 12; ++t12) {
    FragU fq, fk;
    fq.u[0] = 0; fq.u[1] = 0; fk.u[0] = 0; fk.u[1] = 0;
    const int tok = t12 * 16 + m;
    if (quad < 2 && tok < kN) {
      fq.q = *(const uint4*)(qg + base + tok * 16 + quad * 8);
      fk.q = *(const uint4*)(kg + base + tok * 16 + quad * 8);
    }
    qfr[t12] = fq.f;
    kfr[t12] = fk.f;
  }

  // ---- Wm A-fragments with interleaved cat-dim mapping:
  // kd (2c,2c+1) in kt=0 -> (o1 chan c, o2 chan c); kt=1 -> (o3, o4).
  bf16x8 wmb[2];
#pragma unroll
  for (int kt = 0; kt < 2; ++kt) {
    FragU f;
#pragma unroll
    for (int j = 0; j < 8; ++j) {
      const int kdl = quad * 8 + j;
      const int orig = (kt * 2 + (kdl & 1)) * 16 + (kdl >> 1);
      f.h[j] = f2bf(Wm[m * 64 + orig]);
    }
    wmb[kt] = f.f;
  }
  const float4 bm4 = *(const float4*)(bm + quad * 4);

  // barrier: s_vT ready AND all waves' qfr/kfr global reads drained before
  // anyone writes mg (aliases qg).
  __syncthreads();

  bf16x8 vb[6];   // V B-frags: B[kd][n] = V[32p+kd][n]
#pragma unroll
  for (int p = 0; p < 6; ++p) {
    FragU f;
    f.q = *(const uint4*)(s_vT + m * 200 + p * 32 + quad * 8);
    vb[p] = f.f;
  }
  FragU onesU; onesU.u[0] = 0x3F803F803F803F80ULL; onesU.u[1] = onesU.u[0];
  const bf16x8 ones = onesU.f;

  u16* stg = s_stage + w * 640;
  u16* cw = s_cat + w * 1152;
  u16* stgw = stg + m * 40 + quad * 4;        // E b64 write base (+h*16)
  const u16* stgr = stg + m * 40 + quad * 8;  // b128 E read base
  const f32x4 zero4 = {0.f, 0.f, 0.f, 0.f};

#pragma unroll
  for (int ti = 0; ti < 3; ++ti) {
    const int tt = w + ti * 4;
    // own-tile B-operands (runtime tt -> global reload; own tile only, safe)
    FragU fqB, fkB;
    fqB.u[0] = 0; fqB.u[1] = 0; fkB.u[0] = 0; fkB.u[1] = 0;
    const int tokB = tt * 16 + m;
    if (quad < 2 && tokB < kN) {
      fqB.q = *(const uint4*)(qg + base + tokB * 16 + quad * 8);
      fkB.q = *(const uint4*)(kg + base + tokB * 16 + quad * 8);
    }
    const bf16x8 qB = fqB.f;
    const bf16x8 kB = fkB.f;

    // ================= row pass (q-tile = tt) =================
    f32x4 o1 = zero4, l1 = zero4, o3 = zero4, o4 = zero4;
#pragma unroll
    for (int p = 0; p < 6; ++p) {
#pragma unroll
      for (int h = 0; h < 2; ++h) {
        f32x4 sv = MFMA(kfr[p * 2 + h], qB, zero4);  // S^T tile
        uint2 ev;
        ev.x = pack_trunc(exp2f(sv[0]), exp2f(sv[1]));
        ev.y = pack_trunc(exp2f(sv[2]), exp2f(sv[3]));
        *(uint2*)(stgw + h * 16) = ev;
      }
      FragU pa; pa.q = *(const uint4*)stgr;   // A = E[qrow][token]
      o1 = MFMA(pa.f, vb[p], o1);
      l1 = MFMA(pa.f, ones, l1);
      FragU a3; a3.q = *(const uint4*)(arr3 + (size_t)((tt * 6 + p) * 64 + lane) * 8);
      FragU a4; a4.q = *(const uint4*)(arr4 + (size_t)((tt * 6 + p) * 64 + lane) * 8);
      o3 = MFMA(a3.f, vb[p], o3);
      o4 = MFMA(a4.f, vb[p], o4);
    }
    // ================= col pass (k-tile = tt) =================
    f32x4 o2 = zero4, l2 = zero4;
#pragma unroll
    for (int p = 0; p < 6; ++p) {
#pragma unroll
      for (int h = 0; h < 2; ++h) {
        f32x4 sv = MFMA(qfr[p * 2 + h], kB, zero4);  // S tile
        uint2 ev;
        ev.x = pack_trunc(exp2f(sv[0]), exp2f(sv[1]));
        ev.y = pack_trunc(exp2f(sv[2]), exp2f(sv[3]));
        *(uint2*)(stgw + h * 16) = ev;
      }
      FragU pa; pa.q = *(const uint4*)stgr;   // A = E^T[kcol][qrow]
      o2 = MFMA(pa.f, vb[p], o2);
      l2 = MFMA(pa.f, ones, l2);
    }
    // ================= fused Wm epilogue =================
#pragma unroll
    for (int r = 0; r < 4; ++r) {
      const int token = quad * 4 + r;
      const float n1 = o1[r] * __builtin_amdgcn_rcpf(l1[r] - 8.0f);
      const float n2 = o2[r] * __builtin_amdgcn_rcpf(l2[r] - 8.0f);
      *(u32*)(cw + token * 72 + 2 * m)      = pack_bf2(n1, n2);       // dims 2m,2m+1
      *(u32*)(cw + token * 72 + 32 + 2 * m) = pack_bf2(o3[r], o4[r]); // dims 32+2m,33+2m
    }
    f32x4 macc = {bm4.x, bm4.y, bm4.z, bm4.w};
#pragma unroll
    for (int kt = 0; kt < 2; ++kt) {
      FragU ca; ca.q = *(const uint4*)(cw + m * 72 + kt * 32 + quad * 8);
      macc = MFMA(wmb[kt], ca.f, macc);   // filt^T = Wm @ cat^T
    }
    if (tt * 16 + m < kN) {
      *(uint2*)(mg + base + (tt * 16 + m) * 16 + quad * 4) =
          make_uint2(pack_bf2(macc[0], macc[1]), pack_bf2(macc[2], macc[3]));
    }
  }
}

// ---------------------------------------------------------------------------
// Kernel 4: MFMA head-merge + Wo GEMM, fp32 out + bo (unchanged).
// ---------------------------------------------------------------------------
__global__ __launch_bounds__(256) void out_kernel(
    const u16* __restrict__ mg, const u16* __restrict__ wob,
    const float* __restrict__ bo, float* __restrict__ outg) {
  __shared__ u16 s_w[128 * 136];
  const int tid = threadIdx.x;
  {
    const uint4* src = (const uint4*)wob;
    for (int i = tid; i < 2048; i += 256) {
      const int row = i >> 4, q16 = i & 15;
      *(uint4*)(s_w + row * 136 + q16 * 8) = src[i];
    }
  }
  __syncthreads();

  const int w = tid >> 6, lane = tid & 63, quad = lane >> 4, m = lane & 15;
  const int r0 = blockIdx.x * 128;

  f32x4 acc0[8], acc1[8];
  const f32x4 z4 = {0.f, 0.f, 0.f, 0.f};
#pragma unroll
  for (int ct = 0; ct < 8; ++ct) { acc0[ct] = z4; acc1[ct] = z4; }

  const int hh = quad >> 1, hd8 = (quad & 1) * 8;
  const int ra = r0 + w * 16 + m;
  const int bt0 = ra / kN, n0 = ra - bt0 * kN;
  const int rb = ra + 64;
  const int bt1 = rb / kN, n1 = rb - bt1 * kN;
  const u16* mp0 = mg + ((size_t)(hh * kBT + bt0) * kN + n0) * 16 + hd8;
  const u16* mp1 = mg + ((size_t)(hh * kBT + bt1) * kN + n1) * 16 + hd8;
  const size_t hstep = (size_t)2 * kBT * kN * 16;

#pragma unroll
  for (int kp = 0; kp < 4; ++kp) {
    FragU a0; a0.q = *(const uint4*)(mp0 + kp * hstep);
    FragU a1; a1.q = *(const uint4*)(mp1 + kp * hstep);
#pragma unroll
    for (int ct = 0; ct < 8; ++ct) {
      FragU bfr; bfr.q = *(const uint4*)(s_w + (ct * 16 + m) * 136 + kp * 32 + quad * 8);
      acc0[ct] = MFMA(a0.f, bfr.f, acc0[ct]);
      acc1[ct] = MFMA(a1.f, bfr.f, acc1[ct]);
    }
  }

  float bc[8];
#pragma unroll
  for (int ct = 0; ct < 8; ++ct) bc[ct] = bo[ct * 16 + m];

#pragma unroll
  for (int half = 0; half < 2; ++half) {
    const f32x4* acc = half ? acc1 : acc0;
    const int rbase = r0 + (w + half * 4) * 16 + quad * 4;
#pragma unroll
    for (int rr = 0; rr < 4; ++rr) {
      float* op = outg + (size_t)(rbase + rr) * 128 + m;
#pragma unroll
      for (int ct = 0; ct < 8; ++ct)
        op[ct * 16] = acc[ct][rr] + bc[ct];
    }
  }
}

// ---------------------------------------------------------------------------
extern "C" void kernel_launch(void* const* d_in, const int* in_sizes, int n_in,
                              void* d_out, int out_size, void* d_ws, size_t ws_size,
                              hipStream_t stream) {
  const float* query = (const float*)d_in[0];
  const float* key   = (const float*)d_in[1];
  const float* value = (const float*)d_in[2];
  const float* Wq = (const float*)d_in[3];
  const float* bq = (const float*)d_in[4];
  const float* Wk = (const float*)d_in[5];
  const float* bk = (const float*)d_in[6];
  const float* Wv = (const float*)d_in[7];
  const float* bv = (const float*)d_in[8];
  const float* Wm = (const float*)d_in[9];
  const float* bm = (const float*)d_in[10];
  const float* Wo = (const float*)d_in[11];
  const float* bo = (const float*)d_in[12];
  const float* ne1 = (const float*)d_in[13];
  const float* ne2 = (const float*)d_in[14];

  const size_t tensor_bytes = (size_t)kH * kB * kT * kN * kHD * 2;  // 12,058,624
  const size_t frag_bytes = (size_t)12 * 6 * 64 * 8 * 2;            // 73,728
  char* ws = (char*)d_ws;
  u16* qs   = (u16*)(ws);                        // reused as m after attn
  u16* ks   = (u16*)(ws + tensor_bytes);
  u16* vs   = (u16*)(ws + 2 * tensor_bytes);
  u16* arr3 = (u16*)(ws + 3 * tensor_bytes);
  u16* arr4 = (u16*)(ws + 3 * tensor_bytes + frag_bytes);
  u16* wb   = (u16*)(ws + 3 * tensor_bytes + 2 * frag_bytes);  // 4x16384 bf16

  wcvt_kernel<<<32, 256, 0, stream>>>(Wq, Wk, Wv, Wo, wb);
  adp_kernel<<<1, 256, 0, stream>>>(ne1, ne2, arr3, arr4);
  proj_kernel<<<dim3(kRows / 128, 3), 256, 0, stream>>>(
      query, key, value, wb, bq, bk, bv, qs, ks, vs);
  attn_kernel<<<kH * kB * kT, 256, 0, stream>>>(qs, ks, vs, arr3, arr4, Wm, bm, qs);
  out_kernel<<<kRows / 128, 256, 0, stream>>>(qs, wb + 49152, bo, (float*)d_out);
}